// Round 1
// 289.621 us; speedup vs baseline: 1.1753x; 1.1753x over previous
//
#include <hip/hip_runtime.h>
#include <hip/hip_bf16.h>
#include <stdint.h>

// Problem constants
#define KK   8192
#define NN   16384      // B*H*W tokens
#define CCH  256        // channels

#define QE_SIZE  4194304            // NN*CCH floats
#define LOSS_OFF QE_SIZE
#define IDX_OFF  (QE_SIZE + 1)

// ws layout (bytes) — ~9.3 MB
#define B2_OFF     0ULL                              // ushort B2[8192][512] = [hi|lo]
#define HN_OFF     (B2_OFF + 8192ULL*512*2)          // float hn[8192]
#define P1D_OFF    (HN_OFF + 8192ULL*4)              // float pd1[4][16384]
#define P1I_OFF    (P1D_OFF + 4ULL*16384*4)          // int   pi1[4][16384]
#define P2D_OFF    (P1I_OFF + 4ULL*16384*4)          // float pd2[4][16384]
#define P2I_OFF    (P2D_OFF + 4ULL*16384*4)          // int   pi2[4][16384]

typedef __attribute__((ext_vector_type(8))) short   bf16x8;
typedef __attribute__((ext_vector_type(8))) unsigned short ushort8v;
typedef __attribute__((ext_vector_type(4))) float   f32x4;

__device__ __forceinline__ void gld16(const void* g, void* l) {
    __builtin_amdgcn_global_load_lds(
        (const __attribute__((address_space(1))) void*)g,
        (__attribute__((address_space(3))) void*)l, 16, 0, 0);
}

// round-to-nearest-even fp32 -> bf16 bits
__device__ __forceinline__ unsigned short bf16_rn(float v) {
    uint32_t u = __float_as_uint(v);
    return (unsigned short)((u + 0x7fffu + ((u >> 16) & 1u)) >> 16);
}

// merge other top-2 (t1,j1,t2,j2) into mine (s1,i1,s2,i2); higher score wins,
// ties -> smaller index (first-occurrence argmin semantics)
__device__ __forceinline__ void top2_merge(float& s1, int& i1, float& s2, int& i2,
                                           float t1, int j1, float t2, int j2) {
    if (t1 > s1 || (t1 == s1 && j1 < i1)) {
        float ns2; int ni2;
        if (s1 > t2 || (s1 == t2 && i1 < j2)) { ns2 = s1; ni2 = i1; }
        else                                   { ns2 = t2; ni2 = j2; }
        s1 = t1; i1 = j1; s2 = ns2; i2 = ni2;
    } else {
        if (t1 > s2 || (t1 == s2 && j1 < i2)) { s2 = t1; i2 = j1; }
    }
}

// ---------------------------------------------------------------------------
// Prep 1: split x -> A-FRAGMENT-MAJOR layout in d_out's qe region (16 MiB).
// For 16-token tile tb = n>>4, virtual k-step ks (0..15 over [hi|lo]),
// lane l: 8 bf16 of token tb*16+(l&15), channels ks*32 + (l>>4)*8.
// Frag addr (elements) = ((tb*16 + ks)*64 + l)*8.
// ---------------------------------------------------------------------------
__global__ __launch_bounds__(256) void split_x_kernel(const float* __restrict__ x,
                                                      unsigned short* __restrict__ A) {
    __shared__ float xt[256 * 64];      // [c][tok] 64 KB
    const int t = threadIdx.x;
    const int n0 = blockIdx.x * 64;
    const int b = n0 >> 10, hw0 = n0 & 1023;
    const int tok_l = t & 63, cg = t >> 6;
    const float* xb = x + ((size_t)b << 18) + hw0 + tok_l;
    #pragma unroll 8
    for (int i = 0; i < 64; ++i) {
        int c = cg * 64 + i;
        xt[c * 64 + tok_l] = xb[(size_t)c << 10];
    }
    __syncthreads();
    const int tokq = t >> 5;            // 8 tokens per pass
    const int c8 = (t & 31) * 8;
    const int ksh = c8 >> 5;            // hi ks
    const int lq  = (c8 >> 3) & 3;      // quad within frag
    for (int p = 0; p < 8; ++p) {
        int tk = p * 8 + tokq;
        unsigned short hi[8], lo[8];
        #pragma unroll
        for (int u = 0; u < 8; ++u) {
            float v = xt[(c8 + u) * 64 + tk];
            unsigned short h = bf16_rn(v);
            float fh = __uint_as_float(((uint32_t)h) << 16);
            lo[u] = bf16_rn(v - fh);
            hi[u] = h;
        }
        const int n  = n0 + tk;
        const int tb = n >> 4;
        const int l  = (tk & 15) + 16 * lq;
        *(ushort8v*)(A + ((size_t)((tb * 16 + ksh)     * 64) + l) * 8) = *(ushort8v*)hi;
        *(ushort8v*)(A + ((size_t)((tb * 16 + 8 + ksh) * 64) + l) * 8) = *(ushort8v*)lo;
    }
}

// ---------------------------------------------------------------------------
// Prep 2: split codebook [8192][256] -> B2[k][512] = [hi | lo] (bf16) and
// hn[k] = 0.5*||e_k||^2 (fp32 exact). 32 threads per code row.
// ---------------------------------------------------------------------------
__global__ __launch_bounds__(256) void split_cb_kernel(const float* __restrict__ cb,
                                                       unsigned short* __restrict__ B2,
                                                       float* __restrict__ hn) {
    const int t = threadIdx.x;
    const int code = blockIdx.x * 8 + (t >> 5);
    const int c8 = (t & 31) * 8;
    const float* cr = cb + (size_t)code * CCH + c8;
    float s = 0.f;
    unsigned short hi[8], lo[8];
    #pragma unroll
    for (int u = 0; u < 8; ++u) {
        float v = cr[u];
        s += v * v;
        unsigned short h = bf16_rn(v);
        float fh = __uint_as_float(((uint32_t)h) << 16);
        lo[u] = bf16_rn(v - fh);
        hi[u] = h;
    }
    unsigned short* Br = B2 + (size_t)code * 512;
    *(ushort8v*)(Br + c8)       = *(ushort8v*)hi;
    *(ushort8v*)(Br + 256 + c8) = *(ushort8v*)lo;
    #pragma unroll
    for (int off = 16; off; off >>= 1) s += __shfl_xor(s, off);
    if ((t & 31) == 0) hn[code] = 0.5f * s;
}

// ---------------------------------------------------------------------------
// Main: bf16 MFMA GEMM, fused TOP-2 of (dot - 0.5||e||^2).  (unchanged)
// ---------------------------------------------------------------------------
__global__ __launch_bounds__(256, 2) void vq_gemm_kernel(const unsigned short* __restrict__ A,
                                                         const unsigned short* __restrict__ B2,
                                                         const float* __restrict__ hn,
                                                         float* __restrict__ pd1,
                                                         int*   __restrict__ pi1,
                                                         float* __restrict__ pd2,
                                                         int*   __restrict__ pi2) {
    __shared__ unsigned short Bsm[2][64 * 64];    // 2 x 8 KB ping-pong

    const int t = threadIdx.x;
    const int lane = t & 63, wave = t >> 6;
    const int l15 = lane & 15, quad = lane >> 4;

    const int mblk = blockIdx.x & 127;        // 128 M-blocks of 128 tokens
    const int nq   = blockIdx.x >> 7;         // 4 code quarters
    const int codeQ = nq * 2048;

    // A fragments: 32 coalesced dwordx4 loads, resident for the whole kernel
    bf16x8 af[2][16];
    #pragma unroll
    for (int i = 0; i < 2; ++i) {
        const int tb = mblk * 8 + wave * 2 + i;   // 16-token tile id
        const unsigned short* Abase = A + ((size_t)(tb * 16) * 64 + lane) * 8;
        #pragma unroll
        for (int ks = 0; ks < 16; ++ks)
            af[i][ks] = *(const bf16x8*)(Abase + (size_t)ks * 64 * 8);
    }

    // B staging geometry (global_load_lds: wave-uniform base + lane*16)
    const int srow = wave * 8 + (lane >> 3);          // + it*32
    const int sch  = (lane & 7) ^ (srow & 7);         // swizzled source chunk

    // stage GN (0..255): ntn = GN>>3 (64-code tile), stn = GN&7
    // stn 0-3: B hi slabs (ch 0/64/128/192); stn 4-7: B lo slabs
#define STAGE_LOAD(GN)                                                         \
    do {                                                                       \
        const int ntn = (GN) >> 3, stn = (GN) & 7;                             \
        const int bkt = (stn & 3) * 64 + (stn >> 2) * 256;                     \
        const size_t bOff = (size_t)(codeQ + ntn * 64 + srow) * 512            \
                            + sch * 8 + bkt;                                   \
        char* dst = (char*)Bsm[(GN) & 1] + wave * 1024;                        \
        _Pragma("unroll")                                                      \
        for (int it = 0; it < 2; ++it)                                         \
            gld16(B2 + bOff + (size_t)it * (32 * 512), dst + it * 4096);       \
    } while (0)

    float rs1[2][4], rs2[2][4];
    int   ri1[2][4], ri2[2][4];
    #pragma unroll
    for (int i = 0; i < 2; ++i)
        #pragma unroll
        for (int r = 0; r < 4; ++r) {
            rs1[i][r] = -1e30f; ri1[i][r] = 0x7ffffff;
            rs2[i][r] = -1e30f; ri2[i][r] = 0x7ffffff;
        }

    STAGE_LOAD(0);                                     // prologue prefetch
    int g = 0;

    #pragma unroll 1
    for (int nt = 0; nt < 32; ++nt) {
        const int code0 = codeQ + nt * 64;
        f32x4 acc[2][4];
        #pragma unroll
        for (int i = 0; i < 2; ++i)
            #pragma unroll
            for (int j = 0; j < 4; ++j) {
                f32x4 z = {0.f, 0.f, 0.f, 0.f};
                acc[i][j] = z;
            }

        #pragma unroll
        for (int st = 0; st < 8; ++st) {
            __syncthreads();                           // stage g drained; prev reads done
            if (g + 1 < 256) STAGE_LOAD(g + 1);        // prefetch under this stage's MFMA
            const char* bs = (const char*)Bsm[g & 1];

            #pragma unroll
            for (int ks2 = 0; ks2 < 2; ++ks2) {
                bf16x8 bfr[4];
                #pragma unroll
                for (int j = 0; j < 4; ++j) {
                    const int rowB = j * 16 + l15;
                    const int cbk = ((quad ^ (rowB & 7)) ^ (ks2 << 2)) * 16;
                    bfr[j] = *(const bf16x8*)(bs + rowB * 128 + cbk);
                }
                if (st < 4) {
                    const int ka = st * 2 + ks2;       // A hi + A lo vs B hi
                    #pragma unroll
                    for (int i = 0; i < 2; ++i) {
                        #pragma unroll
                        for (int j = 0; j < 4; ++j)
                            acc[i][j] = __builtin_amdgcn_mfma_f32_16x16x32_bf16(
                                af[i][ka], bfr[j], acc[i][j], 0, 0, 0);
                        #pragma unroll
                        for (int j = 0; j < 4; ++j)
                            acc[i][j] = __builtin_amdgcn_mfma_f32_16x16x32_bf16(
                                af[i][8 + ka], bfr[j], acc[i][j], 0, 0, 0);
                    }
                } else {
                    const int ka = (st - 4) * 2 + ks2; // A hi vs B lo
                    #pragma unroll
                    for (int i = 0; i < 2; ++i)
                        #pragma unroll
                        for (int j = 0; j < 4; ++j)
                            acc[i][j] = __builtin_amdgcn_mfma_f32_16x16x32_bf16(
                                af[i][ka], bfr[j], acc[i][j], 0, 0, 0);
                }
            }
            ++g;
        }

        // epilogue: top-2 of s = dot - 0.5||e||^2 (strict >, codes ascend)
        #pragma unroll
        for (int j = 0; j < 4; ++j) {
            const int cg = code0 + j * 16 + l15;
            const float h = hn[cg];
            #pragma unroll
            for (int i = 0; i < 2; ++i)
                #pragma unroll
                for (int r = 0; r < 4; ++r) {
                    const float s = acc[i][j][r] - h;
                    if (s > rs1[i][r]) {
                        rs2[i][r] = rs1[i][r]; ri2[i][r] = ri1[i][r];
                        rs1[i][r] = s;         ri1[i][r] = cg;
                    } else if (s > rs2[i][r]) {
                        rs2[i][r] = s; ri2[i][r] = cg;
                    }
                }
        }
    }
#undef STAGE_LOAD

    // top-2 butterfly across the 16-lane col groups (same tokens)
    #pragma unroll
    for (int off = 1; off < 16; off <<= 1) {
        #pragma unroll
        for (int i = 0; i < 2; ++i)
            #pragma unroll
            for (int r = 0; r < 4; ++r) {
                const float t1 = __shfl_xor(rs1[i][r], off);
                const int   j1 = __shfl_xor(ri1[i][r], off);
                const float t2 = __shfl_xor(rs2[i][r], off);
                const int   j2 = __shfl_xor(ri2[i][r], off);
                top2_merge(rs1[i][r], ri1[i][r], rs2[i][r], ri2[i][r],
                           t1, j1, t2, j2);
            }
    }

    // l15==0 lanes hold finals for tokens mblk*128 + wave*32 + i*16 + quad*4 + r
    if (l15 == 0) {
        #pragma unroll
        for (int i = 0; i < 2; ++i)
            #pragma unroll
            for (int r = 0; r < 4; ++r) {
                const int tok = mblk * 128 + wave * 32 + i * 16 + quad * 4 + r;
                const int gi = nq * NN + tok;
                pd1[gi] = rs1[i][r]; pi1[gi] = ri1[i][r];
                pd2[gi] = rs2[i][r]; pi2[gi] = ri2[i][r];
            }
    }
}

// ---------------------------------------------------------------------------
// Finalize v2 (transpose-fused): one block per 64-token group (grid = 256).
// All global traffic coalesced via an LDS [c][tok] transpose (+1 pad):
//   A) merge quarter top-2s (coalesced partial reads)
//   B) stage x tile transposed (lanes over hw -> 256B coalesced reads)
//   R) fp64 rescore, 4 threads/token, per-thread sequential float4 cb reads
//   P) pick best, idx write, one loss atomic per block
//   C) reload chosen code rows ROW-contiguous (coalesced) into same LDS buf
//   D) write qe with lanes over hw -> 256B coalesced stores
// Replaces the old per-wave kernel whose stride-4096B 4B accesses cost
// 64 cache lines per instruction (+ partial-line HBM writes on qe).
// ---------------------------------------------------------------------------
__global__ __launch_bounds__(256) void finalize_kernel(const float* __restrict__ x,
                                                       const float* __restrict__ cb,
                                                       const float* __restrict__ pd1,
                                                       const int*   __restrict__ pi1,
                                                       const float* __restrict__ pd2,
                                                       const int*   __restrict__ pi2,
                                                       float* __restrict__ qe,
                                                       float* __restrict__ idx_f,
                                                       float* __restrict__ loss) {
    __shared__ float  xt[256 * 65];     // [c][tok] transposed tile, 65-pad; reused for e rows
    __shared__ int    i1s[64], i2s[64], bsx[64];
    __shared__ double dp1[4][64], dp2[4][64];

    const int t = threadIdx.x;
    const int n0 = blockIdx.x * 64;
    const int b = n0 >> 10, hw0 = n0 & 1023;
    const int tok_l = t & 63, cg = t >> 6;

    // Phase A: per-token top-2 merge over the 4 code quarters (wave 0)
    if (t < 64) {
        float s1 = -1e30f, s2 = -1e30f; int i1 = 0, i2 = 1;
        const int n = n0 + t;
        #pragma unroll
        for (int q = 0; q < 4; ++q) {
            const int g = q * NN + n;
            top2_merge(s1, i1, s2, i2, pd1[g], pi1[g], pd2[g], pi2[g]);
        }
        i1s[t] = i1; i2s[t] = i2;
    }

    // Phase B: stage x transposed, fully coalesced (lane = hw)
    const float* xb = x + ((size_t)b << 18) + hw0 + tok_l;
    #pragma unroll 8
    for (int i = 0; i < 64; ++i) {
        const int c = cg * 64 + i;
        xt[c * 65 + tok_l] = xb[(size_t)c << 10];
    }
    __syncthreads();

    // Phase R: fp64 rescore of both candidates; 4 threads per token
    {
        const int tok = t & 63, cq = t >> 6;
        const float* c1 = cb + (size_t)i1s[tok] * CCH + cq * 64;
        const float* c2 = cb + (size_t)i2s[tok] * CCH + cq * 64;
        double d1 = 0.0, d2 = 0.0;
        #pragma unroll
        for (int j = 0; j < 64; j += 4) {
            const f32x4 e1 = *(const f32x4*)(c1 + j);
            const f32x4 e2 = *(const f32x4*)(c2 + j);
            #pragma unroll
            for (int u = 0; u < 4; ++u) {
                const float xv = xt[(cq * 64 + j + u) * 65 + tok];
                const double dx1 = (double)xv - (double)e1[u];
                const double dx2 = (double)xv - (double)e2[u];
                d1 += dx1 * dx1;
                d2 += dx2 * dx2;
            }
        }
        dp1[cq][tok] = d1; dp2[cq][tok] = d2;
    }
    __syncthreads();

    // Phase P: pick best per token (wave 0), write idx, block loss atomic
    if (t < 64) {
        const double d1 = dp1[0][t] + dp1[1][t] + dp1[2][t] + dp1[3][t];
        const double d2 = dp2[0][t] + dp2[1][t] + dp2[2][t] + dp2[3][t];
        const int i1 = i1s[t], i2 = i2s[t];
        const bool pick2 = (d2 < d1 || (d2 == d1 && i2 < i1));
        const int best = pick2 ? i2 : i1;
        bsx[t] = best;
        idx_f[n0 + t] = (float)best;
        float lsum = (float)(pick2 ? d2 : d1);
        #pragma unroll
        for (int off = 32; off; off >>= 1) lsum += __shfl_down(lsum, off);
        if (t == 0) atomicAdd(loss, lsum * (1.0f / ((float)NN * (float)CCH)));
    }
    __syncthreads();

    // Phase C: load chosen code rows (row-contiguous, coalesced) into xt
    {
        const int w = t >> 6, lane = t & 63;
        #pragma unroll 4
        for (int i = 0; i < 16; ++i) {
            const int tok = w * 16 + i;
            const float* e = cb + (size_t)bsx[tok] * CCH;
            #pragma unroll
            for (int u = 0; u < 4; ++u) {
                const int c = u * 64 + lane;
                xt[c * 65 + tok] = e[c];
            }
        }
    }
    __syncthreads();

    // Phase D: write qe coalesced from the transposed LDS (lane = hw)
    float* qb = qe + ((size_t)b << 18) + hw0 + tok_l;
    #pragma unroll 8
    for (int i = 0; i < 64; ++i) {
        const int c = cg * 64 + i;
        qb[(size_t)c << 10] = xt[c * 65 + tok_l];
    }
}

// ---------------------------------------------------------------------------
extern "C" void kernel_launch(void* const* d_in, const int* in_sizes, int n_in,
                              void* d_out, int out_size, void* d_ws, size_t ws_size,
                              hipStream_t stream) {
    const float* x  = (const float*)d_in[0];
    const float* cb = (const float*)d_in[1];
    float* out = (float*)d_out;
    char* ws = (char*)d_ws;

    // A (frag-major) lives in d_out's qe region (16 MiB); finalize rewrites qe.
    unsigned short* A  = (unsigned short*)out;
    unsigned short* B2 = (unsigned short*)(ws + B2_OFF);
    float* hn  = (float*)(ws + HN_OFF);
    float* pd1 = (float*)(ws + P1D_OFF);
    int*   pi1 = (int*)(ws + P1I_OFF);
    float* pd2 = (float*)(ws + P2D_OFF);
    int*   pi2 = (int*)(ws + P2I_OFF);

    split_x_kernel <<<NN / 64, 256, 0, stream>>>(x, A);
    split_cb_kernel<<<KK / 8, 256, 0, stream>>>(cb, B2, hn);
    vq_gemm_kernel <<<512, 256, 0, stream>>>(A, B2, hn, pd1, pi1, pd2, pi2);
    hipMemsetAsync(out + LOSS_OFF, 0, sizeof(float), stream);
    finalize_kernel<<<NN / 64, 256, 0, stream>>>(x, cb, pd1, pi1, pd2, pi2,
                                                 out, out + IDX_OFF,
                                                 out + LOSS_OFF);
}

// Round 2
// 281.466 us; speedup vs baseline: 1.2094x; 1.0290x over previous
//
#include <hip/hip_runtime.h>
#include <hip/hip_bf16.h>
#include <stdint.h>

// Problem constants
#define KK   8192
#define NN   16384      // B*H*W tokens
#define CCH  256        // channels

#define QE_SIZE  4194304            // NN*CCH floats
#define LOSS_OFF QE_SIZE
#define IDX_OFF  (QE_SIZE + 1)

// ws layout (bytes) — ~9.3 MB
#define B2_OFF     0ULL                              // ushort B2[8192][512] = [hi|lo]
#define HN_OFF     (B2_OFF + 8192ULL*512*2)          // float hn[8192]
#define P1D_OFF    (HN_OFF + 8192ULL*4)              // float pd1[4][16384]
#define P1I_OFF    (P1D_OFF + 4ULL*16384*4)          // int   pi1[4][16384]
#define P2D_OFF    (P1I_OFF + 4ULL*16384*4)          // float pd2[4][16384]
#define P2I_OFF    (P2D_OFF + 4ULL*16384*4)          // int   pi2[4][16384]

typedef __attribute__((ext_vector_type(8))) short   bf16x8;
typedef __attribute__((ext_vector_type(8))) unsigned short ushort8v;
typedef __attribute__((ext_vector_type(4))) float   f32x4;

__device__ __forceinline__ void gld16(const void* g, void* l) {
    __builtin_amdgcn_global_load_lds(
        (const __attribute__((address_space(1))) void*)g,
        (__attribute__((address_space(3))) void*)l, 16, 0, 0);
}

// round-to-nearest-even fp32 -> bf16 bits
__device__ __forceinline__ unsigned short bf16_rn(float v) {
    uint32_t u = __float_as_uint(v);
    return (unsigned short)((u + 0x7fffu + ((u >> 16) & 1u)) >> 16);
}

// merge other top-2 (t1,j1,t2,j2) into mine (s1,i1,s2,i2); higher score wins,
// ties -> smaller index (first-occurrence argmin semantics)
__device__ __forceinline__ void top2_merge(float& s1, int& i1, float& s2, int& i2,
                                           float t1, int j1, float t2, int j2) {
    if (t1 > s1 || (t1 == s1 && j1 < i1)) {
        float ns2; int ni2;
        if (s1 > t2 || (s1 == t2 && i1 < j2)) { ns2 = s1; ni2 = i1; }
        else                                   { ns2 = t2; ni2 = j2; }
        s1 = t1; i1 = j1; s2 = ns2; i2 = ni2;
    } else {
        if (t1 > s2 || (t1 == s2 && j1 < i2)) { s2 = t1; i2 = j1; }
    }
}

// ---------------------------------------------------------------------------
// Prep 1: split x -> A-FRAGMENT-MAJOR layout in d_out's qe region (16 MiB).
// LDS tile is XOR-swizzled: value (c, tok) lives at xt[c*64 + (tok ^ ((c>>3)&31))].
// Write phase: swizzle uniform per instr, lanes vary tok  -> conflict-free.
// Read phase:  lanes vary c>>3 (= t&31), tk shared        -> spans 32 banks.
// (Previous layout had a 32-way conflict on the read: stride 64 words == bank 0.)
// ---------------------------------------------------------------------------
__global__ __launch_bounds__(256) void split_x_kernel(const float* __restrict__ x,
                                                      unsigned short* __restrict__ A) {
    __shared__ float xt[256 * 64];      // 64 KB, swizzled [c][tok]
    const int t = threadIdx.x;
    const int n0 = blockIdx.x * 64;
    const int b = n0 >> 10, hw0 = n0 & 1023;
    const int tok_l = t & 63, cg = t >> 6;
    const float* xb = x + ((size_t)b << 18) + hw0 + tok_l;
    #pragma unroll 8
    for (int i = 0; i < 64; ++i) {
        const int c = cg * 64 + i;
        xt[c * 64 + (tok_l ^ ((c >> 3) & 31))] = xb[(size_t)c << 10];
    }
    __syncthreads();
    const int tokq = t >> 5;            // 8 tokens per pass
    const int c8 = (t & 31) * 8;
    const int sw = (c8 >> 3) & 31;      // swizzle, uniform over u
    const int ksh = c8 >> 5;            // hi ks
    const int lq  = (c8 >> 3) & 3;      // quad within frag
    for (int p = 0; p < 8; ++p) {
        int tk = p * 8 + tokq;
        const int tks = tk ^ sw;
        unsigned short hi[8], lo[8];
        #pragma unroll
        for (int u = 0; u < 8; ++u) {
            float v = xt[(c8 + u) * 64 + tks];
            unsigned short h = bf16_rn(v);
            float fh = __uint_as_float(((uint32_t)h) << 16);
            lo[u] = bf16_rn(v - fh);
            hi[u] = h;
        }
        const int n  = n0 + tk;
        const int tb = n >> 4;
        const int l  = (tk & 15) + 16 * lq;
        *(ushort8v*)(A + ((size_t)((tb * 16 + ksh)     * 64) + l) * 8) = *(ushort8v*)hi;
        *(ushort8v*)(A + ((size_t)((tb * 16 + 8 + ksh) * 64) + l) * 8) = *(ushort8v*)lo;
    }
}

// ---------------------------------------------------------------------------
// Prep 2: split codebook [8192][256] -> B2[k][512] = [hi | lo] (bf16) and
// hn[k] = 0.5*||e_k||^2 (fp32 exact). 32 threads per code row.
// Also zeroes the loss accumulator (replaces a separate memset launch).
// ---------------------------------------------------------------------------
__global__ __launch_bounds__(256) void split_cb_kernel(const float* __restrict__ cb,
                                                       unsigned short* __restrict__ B2,
                                                       float* __restrict__ hn,
                                                       float* __restrict__ loss) {
    if (blockIdx.x == 0 && threadIdx.x == 0) *loss = 0.f;
    const int t = threadIdx.x;
    const int code = blockIdx.x * 8 + (t >> 5);
    const int c8 = (t & 31) * 8;
    const float* cr = cb + (size_t)code * CCH + c8;
    float s = 0.f;
    unsigned short hi[8], lo[8];
    #pragma unroll
    for (int u = 0; u < 8; ++u) {
        float v = cr[u];
        s += v * v;
        unsigned short h = bf16_rn(v);
        float fh = __uint_as_float(((uint32_t)h) << 16);
        lo[u] = bf16_rn(v - fh);
        hi[u] = h;
    }
    unsigned short* Br = B2 + (size_t)code * 512;
    *(ushort8v*)(Br + c8)       = *(ushort8v*)hi;
    *(ushort8v*)(Br + 256 + c8) = *(ushort8v*)lo;
    #pragma unroll
    for (int off = 16; off; off >>= 1) s += __shfl_xor(s, off);
    if ((t & 31) == 0) hn[code] = 0.5f * s;
}

// ---------------------------------------------------------------------------
// Main: bf16 MFMA GEMM, fused TOP-2 of (dot - 0.5||e||^2).
// v3 pipeline: 4-buffer LDS ring, prefetch depth 3, raw s_barrier + counted
// s_waitcnt vmcnt(4) (never 0 in the main loop). Safety: barrier-per-stage
// bounds wave skew to 1 stage, so the write into buf[(g+3)&3] can never
// collide with any wave's reads of buf[g&3]. hn[] for the quarter is staged
// to LDS in the prologue so the top-2 epilogue issues no vmem (a global hn
// load would force a full vmcnt drain once per N-tile). setprio(1) around
// the MFMA clusters (T5).
// ---------------------------------------------------------------------------
__global__ __launch_bounds__(256, 2) void vq_gemm_kernel(const unsigned short* __restrict__ A,
                                                         const unsigned short* __restrict__ B2,
                                                         const float* __restrict__ hn,
                                                         float* __restrict__ pd1,
                                                         int*   __restrict__ pi1,
                                                         float* __restrict__ pd2,
                                                         int*   __restrict__ pi2) {
    __shared__ unsigned short Bsm[4][64 * 64];    // 4 x 8 KB ring
    __shared__ float hn_sm[2048];                 // 8 KB, this quarter's 0.5||e||^2

    const int t = threadIdx.x;
    const int lane = t & 63, wave = t >> 6;
    const int l15 = lane & 15, quad = lane >> 4;

    const int mblk = blockIdx.x & 127;        // 128 M-blocks of 128 tokens
    const int nq   = blockIdx.x >> 7;         // 4 code quarters
    const int codeQ = nq * 2048;

    // A fragments: 32 coalesced dwordx4 loads, resident for the whole kernel
    bf16x8 af[2][16];
    #pragma unroll
    for (int i = 0; i < 2; ++i) {
        const int tb = mblk * 8 + wave * 2 + i;   // 16-token tile id
        const unsigned short* Abase = A + ((size_t)(tb * 16) * 64 + lane) * 8;
        #pragma unroll
        for (int ks = 0; ks < 16; ++ks)
            af[i][ks] = *(const bf16x8*)(Abase + (size_t)ks * 64 * 8);
    }

    // hn quarter -> LDS (8 KB, 2 x 1KB wave-instrs per wave)
    #pragma unroll
    for (int i = 0; i < 2; ++i) {
        const int boff = (wave * 2 + i) * 1024;               // wave-uniform LDS base
        gld16((const char*)(hn + codeQ) + boff + lane * 16,   // per-lane global
              (char*)hn_sm + boff);
    }

    // B staging geometry (global_load_lds: wave-uniform base + lane*16)
    const int srow = wave * 8 + (lane >> 3);          // + it*32
    const int sch  = (lane & 7) ^ (srow & 7);         // swizzled source chunk

    // stage GN (0..255): ntn = GN>>3 (64-code tile), stn = GN&7
    // stn 0-3: B hi slabs (ch 0/64/128/192); stn 4-7: B lo slabs
#define STAGE_LOAD(GN)                                                         \
    do {                                                                       \
        const int ntn = (GN) >> 3, stn = (GN) & 7;                             \
        const int bkt = (stn & 3) * 64 + (stn >> 2) * 256;                     \
        const size_t bOff = (size_t)(codeQ + ntn * 64 + srow) * 512            \
                            + sch * 8 + bkt;                                   \
        char* dst = (char*)Bsm[(GN) & 3] + wave * 1024;                        \
        _Pragma("unroll")                                                      \
        for (int it = 0; it < 2; ++it)                                         \
            gld16(B2 + bOff + (size_t)it * (32 * 512), dst + it * 4096);       \
    } while (0)

    float rs1[2][4], rs2[2][4];
    int   ri1[2][4], ri2[2][4];
    #pragma unroll
    for (int i = 0; i < 2; ++i)
        #pragma unroll
        for (int r = 0; r < 4; ++r) {
            rs1[i][r] = -1e30f; ri1[i][r] = 0x7ffffff;
            rs2[i][r] = -1e30f; ri2[i][r] = 0x7ffffff;
        }

    // prologue: 3 stages in flight (+2 hn loads, drained by the first wait)
    STAGE_LOAD(0);
    STAGE_LOAD(1);
    STAGE_LOAD(2);
    int g = 0;

    #pragma unroll 1
    for (int nt = 0; nt < 32; ++nt) {
        f32x4 acc[2][4];
        #pragma unroll
        for (int i = 0; i < 2; ++i)
            #pragma unroll
            for (int j = 0; j < 4; ++j) {
                f32x4 z = {0.f, 0.f, 0.f, 0.f};
                acc[i][j] = z;
            }

        #pragma unroll
        for (int st = 0; st < 8; ++st) {
            // my stage-g loads landed (2 newest stages may stay in flight)
            asm volatile("s_waitcnt vmcnt(4)" ::: "memory");
            __builtin_amdgcn_s_barrier();      // all waves' stage-g loads landed
            // prefetch 3 ahead; wraps into retired buffers at the tail to keep
            // the vmcnt invariant uniform (always 6 in flight at the wait)
            STAGE_LOAD((g + 3) & 255);
            const char* bs = (const char*)Bsm[g & 3];

            #pragma unroll
            for (int ks2 = 0; ks2 < 2; ++ks2) {
                bf16x8 bfr[4];
                #pragma unroll
                for (int j = 0; j < 4; ++j) {
                    const int rowB = j * 16 + l15;
                    const int cbk = ((quad ^ (rowB & 7)) ^ (ks2 << 2)) * 16;
                    bfr[j] = *(const bf16x8*)(bs + rowB * 128 + cbk);
                }
                __builtin_amdgcn_s_setprio(1);
                if (st < 4) {
                    const int ka = st * 2 + ks2;       // A hi + A lo vs B hi
                    #pragma unroll
                    for (int i = 0; i < 2; ++i) {
                        #pragma unroll
                        for (int j = 0; j < 4; ++j)
                            acc[i][j] = __builtin_amdgcn_mfma_f32_16x16x32_bf16(
                                af[i][ka], bfr[j], acc[i][j], 0, 0, 0);
                        #pragma unroll
                        for (int j = 0; j < 4; ++j)
                            acc[i][j] = __builtin_amdgcn_mfma_f32_16x16x32_bf16(
                                af[i][8 + ka], bfr[j], acc[i][j], 0, 0, 0);
                    }
                } else {
                    const int ka = (st - 4) * 2 + ks2; // A hi vs B lo
                    #pragma unroll
                    for (int i = 0; i < 2; ++i)
                        #pragma unroll
                        for (int j = 0; j < 4; ++j)
                            acc[i][j] = __builtin_amdgcn_mfma_f32_16x16x32_bf16(
                                af[i][ka], bfr[j], acc[i][j], 0, 0, 0);
                }
                __builtin_amdgcn_s_setprio(0);
            }
            ++g;
        }

        // epilogue: top-2 of s = dot - 0.5||e||^2 (strict >, codes ascend)
        // hn comes from LDS -> no vmem in the loop body, vmcnt stays counted
        #pragma unroll
        for (int j = 0; j < 4; ++j) {
            const int lc = nt * 64 + j * 16 + l15;
            const float h = hn_sm[lc];
            const int cg = codeQ + lc;
            #pragma unroll
            for (int i = 0; i < 2; ++i)
                #pragma unroll
                for (int r = 0; r < 4; ++r) {
                    const float s = acc[i][j][r] - h;
                    if (s > rs1[i][r]) {
                        rs2[i][r] = rs1[i][r]; ri2[i][r] = ri1[i][r];
                        rs1[i][r] = s;         ri1[i][r] = cg;
                    } else if (s > rs2[i][r]) {
                        rs2[i][r] = s; ri2[i][r] = cg;
                    }
                }
        }
    }
#undef STAGE_LOAD

    // top-2 butterfly across the 16-lane col groups (same tokens)
    #pragma unroll
    for (int off = 1; off < 16; off <<= 1) {
        #pragma unroll
        for (int i = 0; i < 2; ++i)
            #pragma unroll
            for (int r = 0; r < 4; ++r) {
                const float t1 = __shfl_xor(rs1[i][r], off);
                const int   j1 = __shfl_xor(ri1[i][r], off);
                const float t2 = __shfl_xor(rs2[i][r], off);
                const int   j2 = __shfl_xor(ri2[i][r], off);
                top2_merge(rs1[i][r], ri1[i][r], rs2[i][r], ri2[i][r],
                           t1, j1, t2, j2);
            }
    }

    // l15==0 lanes hold finals for tokens mblk*128 + wave*32 + i*16 + quad*4 + r
    if (l15 == 0) {
        #pragma unroll
        for (int i = 0; i < 2; ++i)
            #pragma unroll
            for (int r = 0; r < 4; ++r) {
                const int tok = mblk * 128 + wave * 32 + i * 16 + quad * 4 + r;
                const int gi = nq * NN + tok;
                pd1[gi] = rs1[i][r]; pi1[gi] = ri1[i][r];
                pd2[gi] = rs2[i][r]; pi2[gi] = ri2[i][r];
            }
    }
}

// ---------------------------------------------------------------------------
// Finalize v2 (transpose-fused): one block per 64-token group (grid = 256).
// All global traffic coalesced via an LDS [c][tok] transpose (+1 pad).
// ---------------------------------------------------------------------------
__global__ __launch_bounds__(256) void finalize_kernel(const float* __restrict__ x,
                                                       const float* __restrict__ cb,
                                                       const float* __restrict__ pd1,
                                                       const int*   __restrict__ pi1,
                                                       const float* __restrict__ pd2,
                                                       const int*   __restrict__ pi2,
                                                       float* __restrict__ qe,
                                                       float* __restrict__ idx_f,
                                                       float* __restrict__ loss) {
    __shared__ float  xt[256 * 65];     // [c][tok] transposed tile, 65-pad; reused for e rows
    __shared__ int    i1s[64], i2s[64], bsx[64];
    __shared__ double dp1[4][64], dp2[4][64];

    const int t = threadIdx.x;
    const int n0 = blockIdx.x * 64;
    const int b = n0 >> 10, hw0 = n0 & 1023;
    const int tok_l = t & 63, cg = t >> 6;

    // Phase A: per-token top-2 merge over the 4 code quarters (wave 0)
    if (t < 64) {
        float s1 = -1e30f, s2 = -1e30f; int i1 = 0, i2 = 1;
        const int n = n0 + t;
        #pragma unroll
        for (int q = 0; q < 4; ++q) {
            const int g = q * NN + n;
            top2_merge(s1, i1, s2, i2, pd1[g], pi1[g], pd2[g], pi2[g]);
        }
        i1s[t] = i1; i2s[t] = i2;
    }

    // Phase B: stage x transposed, fully coalesced (lane = hw)
    const float* xb = x + ((size_t)b << 18) + hw0 + tok_l;
    #pragma unroll 8
    for (int i = 0; i < 64; ++i) {
        const int c = cg * 64 + i;
        xt[c * 65 + tok_l] = xb[(size_t)c << 10];
    }
    __syncthreads();

    // Phase R: fp64 rescore of both candidates; 4 threads per token
    {
        const int tok = t & 63, cq = t >> 6;
        const float* c1 = cb + (size_t)i1s[tok] * CCH + cq * 64;
        const float* c2 = cb + (size_t)i2s[tok] * CCH + cq * 64;
        double d1 = 0.0, d2 = 0.0;
        #pragma unroll
        for (int j = 0; j < 64; j += 4) {
            const f32x4 e1 = *(const f32x4*)(c1 + j);
            const f32x4 e2 = *(const f32x4*)(c2 + j);
            #pragma unroll
            for (int u = 0; u < 4; ++u) {
                const float xv = xt[(cq * 64 + j + u) * 65 + tok];
                const double dx1 = (double)xv - (double)e1[u];
                const double dx2 = (double)xv - (double)e2[u];
                d1 += dx1 * dx1;
                d2 += dx2 * dx2;
            }
        }
        dp1[cq][tok] = d1; dp2[cq][tok] = d2;
    }
    __syncthreads();

    // Phase P: pick best per token (wave 0), write idx, block loss atomic
    if (t < 64) {
        const double d1 = dp1[0][t] + dp1[1][t] + dp1[2][t] + dp1[3][t];
        const double d2 = dp2[0][t] + dp2[1][t] + dp2[2][t] + dp2[3][t];
        const int i1 = i1s[t], i2 = i2s[t];
        const bool pick2 = (d2 < d1 || (d2 == d1 && i2 < i1));
        const int best = pick2 ? i2 : i1;
        bsx[t] = best;
        idx_f[n0 + t] = (float)best;
        float lsum = (float)(pick2 ? d2 : d1);
        #pragma unroll
        for (int off = 32; off; off >>= 1) lsum += __shfl_down(lsum, off);
        if (t == 0) atomicAdd(loss, lsum * (1.0f / ((float)NN * (float)CCH)));
    }
    __syncthreads();

    // Phase C: load chosen code rows (row-contiguous, coalesced) into xt
    {
        const int w = t >> 6, lane = t & 63;
        #pragma unroll 4
        for (int i = 0; i < 16; ++i) {
            const int tok = w * 16 + i;
            const float* e = cb + (size_t)bsx[tok] * CCH;
            #pragma unroll
            for (int u = 0; u < 4; ++u) {
                const int c = u * 64 + lane;
                xt[c * 65 + tok] = e[c];
            }
        }
    }
    __syncthreads();

    // Phase D: write qe coalesced from the transposed LDS (lane = hw)
    float* qb = qe + ((size_t)b << 18) + hw0 + tok_l;
    #pragma unroll 8
    for (int i = 0; i < 64; ++i) {
        const int c = cg * 64 + i;
        qb[(size_t)c << 10] = xt[c * 65 + tok_l];
    }
}

// ---------------------------------------------------------------------------
extern "C" void kernel_launch(void* const* d_in, const int* in_sizes, int n_in,
                              void* d_out, int out_size, void* d_ws, size_t ws_size,
                              hipStream_t stream) {
    const float* x  = (const float*)d_in[0];
    const float* cb = (const float*)d_in[1];
    float* out = (float*)d_out;
    char* ws = (char*)d_ws;

    // A (frag-major) lives in d_out's qe region (16 MiB); finalize rewrites qe.
    unsigned short* A  = (unsigned short*)out;
    unsigned short* B2 = (unsigned short*)(ws + B2_OFF);
    float* hn  = (float*)(ws + HN_OFF);
    float* pd1 = (float*)(ws + P1D_OFF);
    int*   pi1 = (int*)(ws + P1I_OFF);
    float* pd2 = (float*)(ws + P2D_OFF);
    int*   pi2 = (int*)(ws + P2I_OFF);

    split_x_kernel <<<NN / 64, 256, 0, stream>>>(x, A);
    split_cb_kernel<<<KK / 8, 256, 0, stream>>>(cb, B2, hn, out + LOSS_OFF);
    vq_gemm_kernel <<<512, 256, 0, stream>>>(A, B2, hn, pd1, pi1, pd2, pi2);
    finalize_kernel<<<NN / 64, 256, 0, stream>>>(x, cb, pd1, pi1, pd2, pi2,
                                                 out, out + IDX_OFF,
                                                 out + LOSS_OFF);
}

// Round 3
// 245.050 us; speedup vs baseline: 1.3891x; 1.1486x over previous
//
#include <hip/hip_runtime.h>
#include <hip/hip_bf16.h>
#include <stdint.h>

// Problem constants
#define KK   8192
#define NN   16384      // B*H*W tokens
#define CCH  256        // channels

#define QE_SIZE  4194304            // NN*CCH floats
#define LOSS_OFF QE_SIZE
#define IDX_OFF  (QE_SIZE + 1)

// ws layout (bytes) — ~5.3 MB
// B2 is HI-ONLY now: score = x·e_hi (2 MFMA products); the dropped x·e_lo
// term has std ~0.018 vs top-gap ~4.6; covered by the top-3 fp64 rescue.
#define B2_OFF     0ULL                              // ushort B2[8192][256] (hi)
#define HN_OFF     (B2_OFF + 8192ULL*256*2)          // float hn[8192]
#define P1D_OFF    (HN_OFF + 8192ULL*4)              // float pd1[4][16384]
#define P1I_OFF    (P1D_OFF + 4ULL*16384*4)          // int   pi1[4][16384]
#define P2D_OFF    (P1I_OFF + 4ULL*16384*4)          // float pd2[4][16384]
#define P2I_OFF    (P2D_OFF + 4ULL*16384*4)          // int   pi2[4][16384]

typedef __attribute__((ext_vector_type(8))) short   bf16x8;
typedef __attribute__((ext_vector_type(8))) unsigned short ushort8v;
typedef __attribute__((ext_vector_type(4))) float   f32x4;

__device__ __forceinline__ void gld16(const void* g, void* l) {
    __builtin_amdgcn_global_load_lds(
        (const __attribute__((address_space(1))) void*)g,
        (__attribute__((address_space(3))) void*)l, 16, 0, 0);
}

// round-to-nearest-even fp32 -> bf16 bits
__device__ __forceinline__ unsigned short bf16_rn(float v) {
    uint32_t u = __float_as_uint(v);
    return (unsigned short)((u + 0x7fffu + ((u >> 16) & 1u)) >> 16);
}

// merge other top-2 into mine; higher score wins, ties -> smaller index
__device__ __forceinline__ void top2_merge(float& s1, int& i1, float& s2, int& i2,
                                           float t1, int j1, float t2, int j2) {
    if (t1 > s1 || (t1 == s1 && j1 < i1)) {
        float ns2; int ni2;
        if (s1 > t2 || (s1 == t2 && i1 < j2)) { ns2 = s1; ni2 = i1; }
        else                                   { ns2 = t2; ni2 = j2; }
        s1 = t1; i1 = j1; s2 = ns2; i2 = ni2;
    } else {
        if (t1 > s2 || (t1 == s2 && j1 < i2)) { s2 = t1; i2 = j1; }
    }
}

// insert (s,i) into a running top-3; ties -> smaller index
__device__ __forceinline__ void top3_insert(float& s1, int& i1, float& s2, int& i2,
                                            float& s3, int& i3, float s, int i) {
    if (s > s1 || (s == s1 && i < i1)) {
        s3 = s2; i3 = i2; s2 = s1; i2 = i1; s1 = s; i1 = i;
    } else if (s > s2 || (s == s2 && i < i2)) {
        s3 = s2; i3 = i2; s2 = s; i2 = i;
    } else if (s > s3 || (s == s3 && i < i3)) {
        s3 = s; i3 = i;
    }
}

// ---------------------------------------------------------------------------
// Prep 1: split x -> A-FRAGMENT-MAJOR layout in d_out's qe region (16 MiB).
// LDS tile XOR-swizzled: (c, tok) lives at xt[c*64 + (tok ^ ((c>>3)&31))].
// Write phase: swizzle uniform per instr, lanes vary tok  -> conflict-free.
// Read phase:  lanes vary c>>3, tk shared                 -> spans 32 banks.
// ---------------------------------------------------------------------------
__global__ __launch_bounds__(256) void split_x_kernel(const float* __restrict__ x,
                                                      unsigned short* __restrict__ A) {
    __shared__ float xt[256 * 64];      // 64 KB, swizzled [c][tok]
    const int t = threadIdx.x;
    const int n0 = blockIdx.x * 64;
    const int b = n0 >> 10, hw0 = n0 & 1023;
    const int tok_l = t & 63, cg = t >> 6;
    const float* xb = x + ((size_t)b << 18) + hw0 + tok_l;
    #pragma unroll 8
    for (int i = 0; i < 64; ++i) {
        const int c = cg * 64 + i;
        xt[c * 64 + (tok_l ^ ((c >> 3) & 31))] = xb[(size_t)c << 10];
    }
    __syncthreads();
    const int tokq = t >> 5;            // 8 tokens per pass
    const int c8 = (t & 31) * 8;
    const int sw = (c8 >> 3) & 31;      // swizzle, uniform over u
    const int ksh = c8 >> 5;            // hi ks
    const int lq  = (c8 >> 3) & 3;      // quad within frag
    for (int p = 0; p < 8; ++p) {
        int tk = p * 8 + tokq;
        const int tks = tk ^ sw;
        unsigned short hi[8], lo[8];
        #pragma unroll
        for (int u = 0; u < 8; ++u) {
            float v = xt[(c8 + u) * 64 + tks];
            unsigned short h = bf16_rn(v);
            float fh = __uint_as_float(((uint32_t)h) << 16);
            lo[u] = bf16_rn(v - fh);
            hi[u] = h;
        }
        const int n  = n0 + tk;
        const int tb = n >> 4;
        const int l  = (tk & 15) + 16 * lq;
        *(ushort8v*)(A + ((size_t)((tb * 16 + ksh)     * 64) + l) * 8) = *(ushort8v*)hi;
        *(ushort8v*)(A + ((size_t)((tb * 16 + 8 + ksh) * 64) + l) * 8) = *(ushort8v*)lo;
    }
}

// ---------------------------------------------------------------------------
// Prep 2: codebook [8192][256] -> B2[k][256] hi-only bf16 and
// hn[k] = 0.5*||e_k||^2 (fp32 exact). 32 threads per code row.
// Also zeroes the loss accumulator.
// ---------------------------------------------------------------------------
__global__ __launch_bounds__(256) void split_cb_kernel(const float* __restrict__ cb,
                                                       unsigned short* __restrict__ B2,
                                                       float* __restrict__ hn,
                                                       float* __restrict__ loss) {
    if (blockIdx.x == 0 && threadIdx.x == 0) *loss = 0.f;
    const int t = threadIdx.x;
    const int code = blockIdx.x * 8 + (t >> 5);
    const int c8 = (t & 31) * 8;
    const float* cr = cb + (size_t)code * CCH + c8;
    float s = 0.f;
    unsigned short hi[8];
    #pragma unroll
    for (int u = 0; u < 8; ++u) {
        float v = cr[u];
        s += v * v;
        hi[u] = bf16_rn(v);
    }
    *(ushort8v*)(B2 + (size_t)code * 256 + c8) = *(ushort8v*)hi;
    #pragma unroll
    for (int off = 16; off; off >>= 1) s += __shfl_xor(s, off);
    if ((t & 31) == 0) hn[code] = 0.5f * s;
}

// ---------------------------------------------------------------------------
// Main: bf16 MFMA GEMM, fused TOP-2 of (x·e_hi - 0.5||e||^2).
// 2 products only: xh·eh + xl·eh = x·eh  (B-lo term dropped; fp64 top-3
// rescue in finalize covers the ~0.018-std score error). 4 stages per
// 64-code N-tile (hi slabs only) -> half the barriers/staging/LDS reads of
// the 3-product version. Round-1 known-good ping-pong sync structure.
// ---------------------------------------------------------------------------
__global__ __launch_bounds__(256, 2) void vq_gemm_kernel(const unsigned short* __restrict__ A,
                                                         const unsigned short* __restrict__ B2,
                                                         const float* __restrict__ hn,
                                                         float* __restrict__ pd1,
                                                         int*   __restrict__ pi1,
                                                         float* __restrict__ pd2,
                                                         int*   __restrict__ pi2) {
    __shared__ unsigned short Bsm[2][64 * 64];    // 2 x 8 KB ping-pong

    const int t = threadIdx.x;
    const int lane = t & 63, wave = t >> 6;
    const int l15 = lane & 15, quad = lane >> 4;

    const int mblk = blockIdx.x & 127;        // 128 M-blocks of 128 tokens
    const int nq   = blockIdx.x >> 7;         // 4 code quarters
    const int codeQ = nq * 2048;

    // A fragments: 32 coalesced dwordx4 loads, resident for the whole kernel
    bf16x8 af[2][16];
    #pragma unroll
    for (int i = 0; i < 2; ++i) {
        const int tb = mblk * 8 + wave * 2 + i;   // 16-token tile id
        const unsigned short* Abase = A + ((size_t)(tb * 16) * 64 + lane) * 8;
        #pragma unroll
        for (int ks = 0; ks < 16; ++ks)
            af[i][ks] = *(const bf16x8*)(Abase + (size_t)ks * 64 * 8);
    }

    // B staging geometry (global_load_lds: wave-uniform base + lane*16)
    const int srow = wave * 8 + (lane >> 3);          // + it*32
    const int sch  = (lane & 7) ^ (srow & 7);         // swizzled source chunk

    // stage GN (0..127): ntn = GN>>2 (64-code tile), stn = GN&3 (64-ch slab)
#define STAGE_LOAD(GN)                                                         \
    do {                                                                       \
        const int ntn = (GN) >> 2, stn = (GN) & 3;                             \
        const size_t bOff = (size_t)(codeQ + ntn * 64 + srow) * 256            \
                            + stn * 64 + sch * 8;                              \
        char* dst = (char*)Bsm[(GN) & 1] + wave * 1024;                        \
        _Pragma("unroll")                                                      \
        for (int it = 0; it < 2; ++it)                                         \
            gld16(B2 + bOff + (size_t)it * (32 * 256), dst + it * 4096);       \
    } while (0)

    float rs1[2][4], rs2[2][4];
    int   ri1[2][4], ri2[2][4];
    #pragma unroll
    for (int i = 0; i < 2; ++i)
        #pragma unroll
        for (int r = 0; r < 4; ++r) {
            rs1[i][r] = -1e30f; ri1[i][r] = 0x7ffffff;
            rs2[i][r] = -1e30f; ri2[i][r] = 0x7ffffff;
        }

    STAGE_LOAD(0);                                     // prologue prefetch
    int g = 0;

    #pragma unroll 1
    for (int nt = 0; nt < 32; ++nt) {
        const int code0 = codeQ + nt * 64;
        f32x4 acc[2][4];
        #pragma unroll
        for (int i = 0; i < 2; ++i)
            #pragma unroll
            for (int j = 0; j < 4; ++j) {
                f32x4 z = {0.f, 0.f, 0.f, 0.f};
                acc[i][j] = z;
            }

        #pragma unroll
        for (int st = 0; st < 4; ++st) {
            __syncthreads();                           // stage g drained; prev reads done
            if (g + 1 < 128) STAGE_LOAD(g + 1);        // prefetch under this stage's MFMA
            const char* bs = (const char*)Bsm[g & 1];

            #pragma unroll
            for (int ks2 = 0; ks2 < 2; ++ks2) {
                bf16x8 bfr[4];
                #pragma unroll
                for (int j = 0; j < 4; ++j) {
                    const int rowB = j * 16 + l15;
                    const int cbk = ((quad ^ (rowB & 7)) ^ (ks2 << 2)) * 16;
                    bfr[j] = *(const bf16x8*)(bs + rowB * 128 + cbk);
                }
                const int ka = st * 2 + ks2;           // K-chunk 0..7
                #pragma unroll
                for (int i = 0; i < 2; ++i) {
                    #pragma unroll
                    for (int j = 0; j < 4; ++j)        // xh·eh
                        acc[i][j] = __builtin_amdgcn_mfma_f32_16x16x32_bf16(
                            af[i][ka], bfr[j], acc[i][j], 0, 0, 0);
                    #pragma unroll
                    for (int j = 0; j < 4; ++j)        // xl·eh
                        acc[i][j] = __builtin_amdgcn_mfma_f32_16x16x32_bf16(
                            af[i][8 + ka], bfr[j], acc[i][j], 0, 0, 0);
                }
            }
            ++g;
        }

        // epilogue: top-2 of s = x·eh - 0.5||e||^2 (strict >, codes ascend)
        #pragma unroll
        for (int j = 0; j < 4; ++j) {
            const int cg = code0 + j * 16 + l15;
            const float h = hn[cg];
            #pragma unroll
            for (int i = 0; i < 2; ++i)
                #pragma unroll
                for (int r = 0; r < 4; ++r) {
                    const float s = acc[i][j][r] - h;
                    if (s > rs1[i][r]) {
                        rs2[i][r] = rs1[i][r]; ri2[i][r] = ri1[i][r];
                        rs1[i][r] = s;         ri1[i][r] = cg;
                    } else if (s > rs2[i][r]) {
                        rs2[i][r] = s; ri2[i][r] = cg;
                    }
                }
        }
    }
#undef STAGE_LOAD

    // top-2 butterfly across the 16-lane col groups (same tokens)
    #pragma unroll
    for (int off = 1; off < 16; off <<= 1) {
        #pragma unroll
        for (int i = 0; i < 2; ++i)
            #pragma unroll
            for (int r = 0; r < 4; ++r) {
                const float t1 = __shfl_xor(rs1[i][r], off);
                const int   j1 = __shfl_xor(ri1[i][r], off);
                const float t2 = __shfl_xor(rs2[i][r], off);
                const int   j2 = __shfl_xor(ri2[i][r], off);
                top2_merge(rs1[i][r], ri1[i][r], rs2[i][r], ri2[i][r],
                           t1, j1, t2, j2);
            }
    }

    // l15==0 lanes hold finals for tokens mblk*128 + wave*32 + i*16 + quad*4 + r
    if (l15 == 0) {
        #pragma unroll
        for (int i = 0; i < 2; ++i)
            #pragma unroll
            for (int r = 0; r < 4; ++r) {
                const int tok = mblk * 128 + wave * 32 + i * 16 + quad * 4 + r;
                const int gi = nq * NN + tok;
                pd1[gi] = rs1[i][r]; pi1[gi] = ri1[i][r];
                pd2[gi] = rs2[i][r]; pi2[gi] = ri2[i][r];
            }
    }
}

// ---------------------------------------------------------------------------
// Finalize v3 (transpose-fused, TOP-3 rescue): one block per 64-token group.
//   A) merge 8 quarter candidates -> top-3 (approx score)
//   B) stage x transposed (coalesced)
//   R) fp64 rescore of all 3 candidates, 4 threads/token
//   P) pick true min of the 3, idx write, one loss atomic per block
//   C) load chosen code rows row-contiguous into LDS
//   D) write qe coalesced
// ---------------------------------------------------------------------------
__global__ __launch_bounds__(256) void finalize_kernel(const float* __restrict__ x,
                                                       const float* __restrict__ cb,
                                                       const float* __restrict__ pd1,
                                                       const int*   __restrict__ pi1,
                                                       const float* __restrict__ pd2,
                                                       const int*   __restrict__ pi2,
                                                       float* __restrict__ qe,
                                                       float* __restrict__ idx_f,
                                                       float* __restrict__ loss) {
    __shared__ float  xt[256 * 65];     // [c][tok] transposed tile, 65-pad; reused for e rows
    __shared__ int    cnd[3][64], bsx[64];
    __shared__ double dp[3][4][64];     // [cand][cq][tok]

    const int t = threadIdx.x;
    const int n0 = blockIdx.x * 64;
    const int b = n0 >> 10, hw0 = n0 & 1023;
    const int tok_l = t & 63, cg = t >> 6;

    // Phase A: top-3 of the 8 per-quarter candidates (wave 0)
    if (t < 64) {
        float s1 = -1e30f, s2 = -1e30f, s3 = -1e30f;
        int   i1 = 0x7ffffff, i2 = 0x7ffffff, i3 = 0x7ffffff;
        const int n = n0 + t;
        #pragma unroll
        for (int q = 0; q < 4; ++q) {
            const int g = q * NN + n;
            top3_insert(s1, i1, s2, i2, s3, i3, pd1[g], pi1[g]);
            top3_insert(s1, i1, s2, i2, s3, i3, pd2[g], pi2[g]);
        }
        cnd[0][t] = i1; cnd[1][t] = i2; cnd[2][t] = i3;
    }

    // Phase B: stage x transposed, fully coalesced (lane = hw)
    const float* xb = x + ((size_t)b << 18) + hw0 + tok_l;
    #pragma unroll 8
    for (int i = 0; i < 64; ++i) {
        const int c = cg * 64 + i;
        xt[c * 65 + tok_l] = xb[(size_t)c << 10];
    }
    __syncthreads();

    // Phase R: fp64 rescore of the 3 candidates; 4 threads per token
    {
        const int tok = t & 63, cq = t >> 6;
        const float* c0 = cb + (size_t)cnd[0][tok] * CCH + cq * 64;
        const float* c1 = cb + (size_t)cnd[1][tok] * CCH + cq * 64;
        const float* c2 = cb + (size_t)cnd[2][tok] * CCH + cq * 64;
        double d0 = 0.0, d1 = 0.0, d2 = 0.0;
        #pragma unroll
        for (int j = 0; j < 64; j += 4) {
            const f32x4 e0 = *(const f32x4*)(c0 + j);
            const f32x4 e1 = *(const f32x4*)(c1 + j);
            const f32x4 e2 = *(const f32x4*)(c2 + j);
            #pragma unroll
            for (int u = 0; u < 4; ++u) {
                const float xv = xt[(cq * 64 + j + u) * 65 + tok];
                const double dx0 = (double)xv - (double)e0[u];
                const double dx1 = (double)xv - (double)e1[u];
                const double dx2 = (double)xv - (double)e2[u];
                d0 += dx0 * dx0;
                d1 += dx1 * dx1;
                d2 += dx2 * dx2;
            }
        }
        dp[0][cq][tok] = d0; dp[1][cq][tok] = d1; dp[2][cq][tok] = d2;
    }
    __syncthreads();

    // Phase P: pick true min of the 3 per token (wave 0), idx, loss atomic
    if (t < 64) {
        double dd[3]; int ii[3];
        #pragma unroll
        for (int c = 0; c < 3; ++c) {
            dd[c] = dp[c][0][t] + dp[c][1][t] + dp[c][2][t] + dp[c][3][t];
            ii[c] = cnd[c][t];
        }
        int bi = ii[0]; double bd = dd[0];
        if (dd[1] < bd || (dd[1] == bd && ii[1] < bi)) { bd = dd[1]; bi = ii[1]; }
        if (dd[2] < bd || (dd[2] == bd && ii[2] < bi)) { bd = dd[2]; bi = ii[2]; }
        bsx[t] = bi;
        idx_f[n0 + t] = (float)bi;
        float lsum = (float)bd;
        #pragma unroll
        for (int off = 32; off; off >>= 1) lsum += __shfl_down(lsum, off);
        if (t == 0) atomicAdd(loss, lsum * (1.0f / ((float)NN * (float)CCH)));
    }
    __syncthreads();

    // Phase C: load chosen code rows (row-contiguous, coalesced) into xt
    {
        const int w = t >> 6, lane = t & 63;
        #pragma unroll 4
        for (int i = 0; i < 16; ++i) {
            const int tok = w * 16 + i;
            const float* e = cb + (size_t)bsx[tok] * CCH;
            #pragma unroll
            for (int u = 0; u < 4; ++u) {
                const int c = u * 64 + lane;
                xt[c * 65 + tok] = e[c];
            }
        }
    }
    __syncthreads();

    // Phase D: write qe coalesced from the transposed LDS (lane = hw)
    float* qb = qe + ((size_t)b << 18) + hw0 + tok_l;
    #pragma unroll 8
    for (int i = 0; i < 64; ++i) {
        const int c = cg * 64 + i;
        qb[(size_t)c << 10] = xt[c * 65 + tok_l];
    }
}

// ---------------------------------------------------------------------------
extern "C" void kernel_launch(void* const* d_in, const int* in_sizes, int n_in,
                              void* d_out, int out_size, void* d_ws, size_t ws_size,
                              hipStream_t stream) {
    const float* x  = (const float*)d_in[0];
    const float* cb = (const float*)d_in[1];
    float* out = (float*)d_out;
    char* ws = (char*)d_ws;

    // A (frag-major) lives in d_out's qe region (16 MiB); finalize rewrites qe.
    unsigned short* A  = (unsigned short*)out;
    unsigned short* B2 = (unsigned short*)(ws + B2_OFF);
    float* hn  = (float*)(ws + HN_OFF);
    float* pd1 = (float*)(ws + P1D_OFF);
    int*   pi1 = (int*)(ws + P1I_OFF);
    float* pd2 = (float*)(ws + P2D_OFF);
    int*   pi2 = (int*)(ws + P2I_OFF);

    split_x_kernel <<<NN / 64, 256, 0, stream>>>(x, A);
    split_cb_kernel<<<KK / 8, 256, 0, stream>>>(cb, B2, hn, out + LOSS_OFF);
    vq_gemm_kernel <<<512, 256, 0, stream>>>(A, B2, hn, pd1, pi1, pd2, pi2);
    finalize_kernel<<<NN / 64, 256, 0, stream>>>(x, cb, pd1, pi1, pd2, pi2,
                                                 out, out + IDX_OFF,
                                                 out + LOSS_OFF);
}

// Round 4
// 218.536 us; speedup vs baseline: 1.5576x; 1.1213x over previous
//
#include <hip/hip_runtime.h>
#include <hip/hip_bf16.h>
#include <stdint.h>

// Problem constants
#define KK   8192
#define NN   16384      // B*H*W tokens
#define CCH  256        // channels

#define QE_SIZE  4194304            // NN*CCH floats
#define LOSS_OFF QE_SIZE
#define IDX_OFF  (QE_SIZE + 1)

// ws layout (bytes)
// B2 is HI-ONLY: score = x·e_hi (2 MFMA products); dropped x·e_lo term has
// std ~0.018, covered by the top-3 fp64 rescue in finalize.
// pk1/pk2: packed top-2 keys per (quarter, token):
//   key = ordered_uint(score) rounded to 2048-ulp, low 11 bits = 2047-local_code
//   (monotone: bigger key = better score, ties -> smaller code index)
#define B2_OFF     0ULL                              // ushort B2[8192][256] (hi)
#define HN_OFF     (B2_OFF + 8192ULL*256*2)          // float hn[8192]
#define PK1_OFF    (HN_OFF + 8192ULL*4)              // uint pk1[4][16384]
#define PK2_OFF    (PK1_OFF + 4ULL*16384*4)          // uint pk2[4][16384]

typedef __attribute__((ext_vector_type(8))) short   bf16x8;
typedef __attribute__((ext_vector_type(8))) unsigned short ushort8v;
typedef __attribute__((ext_vector_type(4))) float   f32x4;

__device__ __forceinline__ void gld16(const void* g, void* l) {
    __builtin_amdgcn_global_load_lds(
        (const __attribute__((address_space(1))) void*)g,
        (__attribute__((address_space(3))) void*)l, 16, 0, 0);
}

// round-to-nearest-even fp32 -> bf16 bits
__device__ __forceinline__ unsigned short bf16_rn(float v) {
    uint32_t u = __float_as_uint(v);
    return (unsigned short)((u + 0x7fffu + ((u >> 16) & 1u)) >> 16);
}

// insert candidate (k, g) into running top-3 (key desc, idx asc on ties)
__device__ __forceinline__ void top3k_insert(unsigned& s1, int& i1,
                                             unsigned& s2, int& i2,
                                             unsigned& s3, int& i3,
                                             unsigned k, int g) {
    if (k > s1 || (k == s1 && g < i1)) {
        s3 = s2; i3 = i2; s2 = s1; i2 = i1; s1 = k; i1 = g;
    } else if (k > s2 || (k == s2 && g < i2)) {
        s3 = s2; i3 = i2; s2 = k; i2 = g;
    } else if (k > s3 || (k == s3 && g < i3)) {
        s3 = k; i3 = g;
    }
}

// ---------------------------------------------------------------------------
// Prep 1: split x -> A-FRAGMENT-MAJOR layout in d_out's qe region (16 MiB).
// LDS tile XOR-swizzled: (c, tok) lives at xt[c*64 + (tok ^ ((c>>3)&31))].
// ---------------------------------------------------------------------------
__global__ __launch_bounds__(256) void split_x_kernel(const float* __restrict__ x,
                                                      unsigned short* __restrict__ A) {
    __shared__ float xt[256 * 64];      // 64 KB, swizzled [c][tok]
    const int t = threadIdx.x;
    const int n0 = blockIdx.x * 64;
    const int b = n0 >> 10, hw0 = n0 & 1023;
    const int tok_l = t & 63, cg = t >> 6;
    const float* xb = x + ((size_t)b << 18) + hw0 + tok_l;
    #pragma unroll 8
    for (int i = 0; i < 64; ++i) {
        const int c = cg * 64 + i;
        xt[c * 64 + (tok_l ^ ((c >> 3) & 31))] = xb[(size_t)c << 10];
    }
    __syncthreads();
    const int tokq = t >> 5;            // 8 tokens per pass
    const int c8 = (t & 31) * 8;
    const int sw = (c8 >> 3) & 31;      // swizzle, uniform over u
    const int ksh = c8 >> 5;            // hi ks
    const int lq  = (c8 >> 3) & 3;      // quad within frag
    for (int p = 0; p < 8; ++p) {
        int tk = p * 8 + tokq;
        const int tks = tk ^ sw;
        unsigned short hi[8], lo[8];
        #pragma unroll
        for (int u = 0; u < 8; ++u) {
            float v = xt[(c8 + u) * 64 + tks];
            unsigned short h = bf16_rn(v);
            float fh = __uint_as_float(((uint32_t)h) << 16);
            lo[u] = bf16_rn(v - fh);
            hi[u] = h;
        }
        const int n  = n0 + tk;
        const int tb = n >> 4;
        const int l  = (tk & 15) + 16 * lq;
        *(ushort8v*)(A + ((size_t)((tb * 16 + ksh)     * 64) + l) * 8) = *(ushort8v*)hi;
        *(ushort8v*)(A + ((size_t)((tb * 16 + 8 + ksh) * 64) + l) * 8) = *(ushort8v*)lo;
    }
}

// ---------------------------------------------------------------------------
// Prep 2: codebook [8192][256] -> B2[k][256] hi-only bf16 and
// hn[k] = 0.5*||e_k||^2 (fp32 exact). Also zeroes the loss accumulator.
// ---------------------------------------------------------------------------
__global__ __launch_bounds__(256) void split_cb_kernel(const float* __restrict__ cb,
                                                       unsigned short* __restrict__ B2,
                                                       float* __restrict__ hn,
                                                       float* __restrict__ loss) {
    if (blockIdx.x == 0 && threadIdx.x == 0) *loss = 0.f;
    const int t = threadIdx.x;
    const int code = blockIdx.x * 8 + (t >> 5);
    const int c8 = (t & 31) * 8;
    const float* cr = cb + (size_t)code * CCH + c8;
    float s = 0.f;
    unsigned short hi[8];
    #pragma unroll
    for (int u = 0; u < 8; ++u) {
        float v = cr[u];
        s += v * v;
        hi[u] = bf16_rn(v);
    }
    *(ushort8v*)(B2 + (size_t)code * 256 + c8) = *(ushort8v*)hi;
    #pragma unroll
    for (int off = 16; off; off >>= 1) s += __shfl_xor(s, off);
    if ((t & 31) == 0) hn[code] = 0.5f * s;
}

// ---------------------------------------------------------------------------
// Main: bf16 MFMA GEMM, fused branchless TOP-2 of (x·e_hi - 0.5||e||^2).
// Epilogue v4: packed uint keys (score upper bits | 11-bit inverted local
// code). Each eval = 6 pack ops + min/max/max; no branches, no index regs,
// no global hn loads (hn staged to LDS in prologue; acc init = -h so the
// MFMA output IS the score). Pipeline: round-1 known-good ping-pong.
// ---------------------------------------------------------------------------
__global__ __launch_bounds__(256, 2) void vq_gemm_kernel(const unsigned short* __restrict__ A,
                                                         const unsigned short* __restrict__ B2,
                                                         const float* __restrict__ hn,
                                                         unsigned* __restrict__ pk1,
                                                         unsigned* __restrict__ pk2) {
    __shared__ unsigned short Bsm[2][64 * 64];    // 2 x 8 KB ping-pong
    __shared__ float hn_sm[2048];                 // 8 KB, this quarter's 0.5||e||^2

    const int t = threadIdx.x;
    const int lane = t & 63, wave = t >> 6;
    const int l15 = lane & 15, quad = lane >> 4;

    const int mblk = blockIdx.x & 127;        // 128 M-blocks of 128 tokens
    const int nq   = blockIdx.x >> 7;         // 4 code quarters
    const int codeQ = nq * 2048;

    // A fragments: 32 coalesced dwordx4 loads, resident for the whole kernel
    bf16x8 af[2][16];
    #pragma unroll
    for (int i = 0; i < 2; ++i) {
        const int tb = mblk * 8 + wave * 2 + i;   // 16-token tile id
        const unsigned short* Abase = A + ((size_t)(tb * 16) * 64 + lane) * 8;
        #pragma unroll
        for (int ks = 0; ks < 16; ++ks)
            af[i][ks] = *(const bf16x8*)(Abase + (size_t)ks * 64 * 8);
    }

    // hn quarter -> LDS (8 KB; 2 x 1 KB wave-instrs per wave)
    #pragma unroll
    for (int i = 0; i < 2; ++i) {
        const int boff = (wave * 2 + i) * 1024;               // wave-uniform LDS base
        gld16((const char*)(hn + codeQ) + boff + lane * 16,   // per-lane global
              (char*)hn_sm + boff);
    }

    // B staging geometry (global_load_lds: wave-uniform base + lane*16)
    const int srow = wave * 8 + (lane >> 3);          // + it*32
    const int sch  = (lane & 7) ^ (srow & 7);         // swizzled source chunk

    // stage GN (0..127): ntn = GN>>2 (64-code tile), stn = GN&3 (64-ch slab)
#define STAGE_LOAD(GN)                                                         \
    do {                                                                       \
        const int ntn = (GN) >> 2, stn = (GN) & 3;                             \
        const size_t bOff = (size_t)(codeQ + ntn * 64 + srow) * 256            \
                            + stn * 64 + sch * 8;                              \
        char* dst = (char*)Bsm[(GN) & 1] + wave * 1024;                        \
        _Pragma("unroll")                                                      \
        for (int it = 0; it < 2; ++it)                                         \
            gld16(B2 + bOff + (size_t)it * (32 * 256), dst + it * 4096);       \
    } while (0)

    unsigned K1[2][4], K2[2][4];
    #pragma unroll
    for (int i = 0; i < 2; ++i)
        #pragma unroll
        for (int r = 0; r < 4; ++r) { K1[i][r] = 0u; K2[i][r] = 0u; }

    STAGE_LOAD(0);                  // prologue prefetch
    __syncthreads();                // hn_sm visible (also drains stage 0, once)
    int g = 0;

    #pragma unroll 1
    for (int nt = 0; nt < 32; ++nt) {
        // acc init = -h : MFMA output is directly the score
        const int hb = nt * 64 + l15;
        const float h0 = hn_sm[hb];
        const float h1 = hn_sm[hb + 16];
        const float h2 = hn_sm[hb + 32];
        const float h3 = hn_sm[hb + 48];
        const float hj[4] = {h0, h1, h2, h3};
        f32x4 acc[2][4];
        #pragma unroll
        for (int i = 0; i < 2; ++i)
            #pragma unroll
            for (int j = 0; j < 4; ++j) {
                const float nh = -hj[j];
                f32x4 z = {nh, nh, nh, nh};
                acc[i][j] = z;
            }

        #pragma unroll
        for (int st = 0; st < 4; ++st) {
            __syncthreads();                           // stage g drained; prev reads done
            if (g + 1 < 128) STAGE_LOAD(g + 1);        // prefetch under this stage's MFMA
            const char* bs = (const char*)Bsm[g & 1];

            #pragma unroll
            for (int ks2 = 0; ks2 < 2; ++ks2) {
                bf16x8 bfr[4];
                #pragma unroll
                for (int j = 0; j < 4; ++j) {
                    const int rowB = j * 16 + l15;
                    const int cbk = ((quad ^ (rowB & 7)) ^ (ks2 << 2)) * 16;
                    bfr[j] = *(const bf16x8*)(bs + rowB * 128 + cbk);
                }
                const int ka = st * 2 + ks2;           // K-chunk 0..7
                #pragma unroll
                for (int i = 0; i < 2; ++i) {
                    #pragma unroll
                    for (int j = 0; j < 4; ++j)        // xh·eh
                        acc[i][j] = __builtin_amdgcn_mfma_f32_16x16x32_bf16(
                            af[i][ka], bfr[j], acc[i][j], 0, 0, 0);
                    #pragma unroll
                    for (int j = 0; j < 4; ++j)        // xl·eh
                        acc[i][j] = __builtin_amdgcn_mfma_f32_16x16x32_bf16(
                            af[i][8 + ka], bfr[j], acc[i][j], 0, 0, 0);
                }
            }
            ++g;
        }

        // epilogue: branchless packed-key top-2
        // key = round2048(ordered_uint(score)) | (2047 - local_code)
        const int icb = 2047 - (nt * 64 + l15);
        #pragma unroll
        for (int j = 0; j < 4; ++j) {
            const unsigned ic = (unsigned)(icb - j * 16);
            #pragma unroll
            for (int i = 0; i < 2; ++i)
                #pragma unroll
                for (int r = 0; r < 4; ++r) {
                    unsigned u = __float_as_uint(acc[i][j][r]);
                    u ^= ((unsigned)((int)u >> 31)) | 0x80000000u;
                    const unsigned k = ((u + 1024u) & 0xFFFFF800u) | ic;
                    const unsigned lo = min(k, K1[i][r]);
                    K1[i][r] = max(k, K1[i][r]);
                    K2[i][r] = max(K2[i][r], lo);
                }
        }
    }
#undef STAGE_LOAD

    // top-2 butterfly across the 16-lane col groups (same tokens)
    #pragma unroll
    for (int off = 1; off < 16; off <<= 1) {
        #pragma unroll
        for (int i = 0; i < 2; ++i)
            #pragma unroll
            for (int r = 0; r < 4; ++r) {
                const unsigned t1 = __shfl_xor(K1[i][r], off);
                const unsigned t2 = __shfl_xor(K2[i][r], off);
                const unsigned lo = min(K1[i][r], t1);
                K1[i][r] = max(K1[i][r], t1);
                K2[i][r] = max(max(K2[i][r], t2), lo);
            }
    }

    // l15==0 lanes hold finals for tokens mblk*128 + wave*32 + i*16 + quad*4 + r
    if (l15 == 0) {
        #pragma unroll
        for (int i = 0; i < 2; ++i)
            #pragma unroll
            for (int r = 0; r < 4; ++r) {
                const int tok = mblk * 128 + wave * 32 + i * 16 + quad * 4 + r;
                const int gi = nq * NN + tok;
                pk1[gi] = K1[i][r]; pk2[gi] = K2[i][r];
            }
    }
}

// ---------------------------------------------------------------------------
// Finalize v4 (transpose-fused, TOP-3 rescue over packed keys):
//   A) merge 8 per-quarter packed keys -> top-3 candidates (decode global idx)
//   B) stage x transposed (coalesced)
//   R) fp64 rescore of all 3 candidates, 4 threads/token
//   P) pick true min of the 3, idx write, one loss atomic per block
//   C) load chosen code rows row-contiguous into LDS
//   D) write qe coalesced
// ---------------------------------------------------------------------------
__global__ __launch_bounds__(256) void finalize_kernel(const float* __restrict__ x,
                                                       const float* __restrict__ cb,
                                                       const unsigned* __restrict__ pk1,
                                                       const unsigned* __restrict__ pk2,
                                                       float* __restrict__ qe,
                                                       float* __restrict__ idx_f,
                                                       float* __restrict__ loss) {
    __shared__ float  xt[256 * 65];     // [c][tok] transposed tile, 65-pad; reused for e rows
    __shared__ int    cnd[3][64], bsx[64];
    __shared__ double dp[3][4][64];     // [cand][cq][tok]

    const int t = threadIdx.x;
    const int n0 = blockIdx.x * 64;
    const int b = n0 >> 10, hw0 = n0 & 1023;
    const int tok_l = t & 63, cg = t >> 6;

    // Phase A: top-3 of the 8 per-quarter packed candidates (wave 0)
    if (t < 64) {
        unsigned s1 = 0u, s2 = 0u, s3 = 0u;
        int i1 = 0x7ffffff, i2 = 0x7ffffff, i3 = 0x7ffffff;
        const int n = n0 + t;
        #pragma unroll
        for (int q = 0; q < 4; ++q) {
            const unsigned ka = pk1[q * NN + n];
            const unsigned kb = pk2[q * NN + n];
            const int ga = q * 2048 + 2047 - (int)(ka & 2047u);
            const int gb = q * 2048 + 2047 - (int)(kb & 2047u);
            top3k_insert(s1, i1, s2, i2, s3, i3, ka, ga);
            top3k_insert(s1, i1, s2, i2, s3, i3, kb, gb);
        }
        cnd[0][t] = i1; cnd[1][t] = i2; cnd[2][t] = i3;
    }

    // Phase B: stage x transposed, fully coalesced (lane = hw)
    const float* xb = x + ((size_t)b << 18) + hw0 + tok_l;
    #pragma unroll 8
    for (int i = 0; i < 64; ++i) {
        const int c = cg * 64 + i;
        xt[c * 65 + tok_l] = xb[(size_t)c << 10];
    }
    __syncthreads();

    // Phase R: fp64 rescore of the 3 candidates; 4 threads per token
    {
        const int tok = t & 63, cq = t >> 6;
        const float* c0 = cb + (size_t)cnd[0][tok] * CCH + cq * 64;
        const float* c1 = cb + (size_t)cnd[1][tok] * CCH + cq * 64;
        const float* c2 = cb + (size_t)cnd[2][tok] * CCH + cq * 64;
        double d0 = 0.0, d1 = 0.0, d2 = 0.0;
        #pragma unroll
        for (int j = 0; j < 64; j += 4) {
            const f32x4 e0 = *(const f32x4*)(c0 + j);
            const f32x4 e1 = *(const f32x4*)(c1 + j);
            const f32x4 e2 = *(const f32x4*)(c2 + j);
            #pragma unroll
            for (int u = 0; u < 4; ++u) {
                const float xv = xt[(cq * 64 + j + u) * 65 + tok];
                const double dx0 = (double)xv - (double)e0[u];
                const double dx1 = (double)xv - (double)e1[u];
                const double dx2 = (double)xv - (double)e2[u];
                d0 += dx0 * dx0;
                d1 += dx1 * dx1;
                d2 += dx2 * dx2;
            }
        }
        dp[0][cq][tok] = d0; dp[1][cq][tok] = d1; dp[2][cq][tok] = d2;
    }
    __syncthreads();

    // Phase P: pick true min of the 3 per token (wave 0), idx, loss atomic
    if (t < 64) {
        double dd[3]; int ii[3];
        #pragma unroll
        for (int c = 0; c < 3; ++c) {
            dd[c] = dp[c][0][t] + dp[c][1][t] + dp[c][2][t] + dp[c][3][t];
            ii[c] = cnd[c][t];
        }
        int bi = ii[0]; double bd = dd[0];
        if (dd[1] < bd || (dd[1] == bd && ii[1] < bi)) { bd = dd[1]; bi = ii[1]; }
        if (dd[2] < bd || (dd[2] == bd && ii[2] < bi)) { bd = dd[2]; bi = ii[2]; }
        bsx[t] = bi;
        idx_f[n0 + t] = (float)bi;
        float lsum = (float)bd;
        #pragma unroll
        for (int off = 32; off; off >>= 1) lsum += __shfl_down(lsum, off);
        if (t == 0) atomicAdd(loss, lsum * (1.0f / ((float)NN * (float)CCH)));
    }
    __syncthreads();

    // Phase C: load chosen code rows (row-contiguous, coalesced) into xt
    {
        const int w = t >> 6, lane = t & 63;
        #pragma unroll 4
        for (int i = 0; i < 16; ++i) {
            const int tok = w * 16 + i;
            const float* e = cb + (size_t)bsx[tok] * CCH;
            #pragma unroll
            for (int u = 0; u < 4; ++u) {
                const int c = u * 64 + lane;
                xt[c * 65 + tok] = e[c];
            }
        }
    }
    __syncthreads();

    // Phase D: write qe coalesced from the transposed LDS (lane = hw)
    float* qb = qe + ((size_t)b << 18) + hw0 + tok_l;
    #pragma unroll 8
    for (int i = 0; i < 64; ++i) {
        const int c = cg * 64 + i;
        qb[(size_t)c << 10] = xt[c * 65 + tok_l];
    }
}

// ---------------------------------------------------------------------------
extern "C" void kernel_launch(void* const* d_in, const int* in_sizes, int n_in,
                              void* d_out, int out_size, void* d_ws, size_t ws_size,
                              hipStream_t stream) {
    const float* x  = (const float*)d_in[0];
    const float* cb = (const float*)d_in[1];
    float* out = (float*)d_out;
    char* ws = (char*)d_ws;

    // A (frag-major) lives in d_out's qe region (16 MiB); finalize rewrites qe.
    unsigned short* A  = (unsigned short*)out;
    unsigned short* B2 = (unsigned short*)(ws + B2_OFF);
    float* hn  = (float*)(ws + HN_OFF);
    unsigned* pk1 = (unsigned*)(ws + PK1_OFF);
    unsigned* pk2 = (unsigned*)(ws + PK2_OFF);

    split_x_kernel <<<NN / 64, 256, 0, stream>>>(x, A);
    split_cb_kernel<<<KK / 8, 256, 0, stream>>>(cb, B2, hn, out + LOSS_OFF);
    vq_gemm_kernel <<<512, 256, 0, stream>>>(A, B2, hn, pk1, pk2);
    finalize_kernel<<<NN / 64, 256, 0, stream>>>(x, cb, pk1, pk2,
                                                 out, out + IDX_OFF,
                                                 out + LOSS_OFF);
}

// Round 5
// 203.358 us; speedup vs baseline: 1.6739x; 1.0746x over previous
//
#include <hip/hip_runtime.h>
#include <hip/hip_bf16.h>
#include <stdint.h>

// Problem constants
#define KK   8192
#define NN   16384      // B*H*W tokens
#define CCH  256        // channels

#define QE_SIZE  4194304            // NN*CCH floats
#define LOSS_OFF QE_SIZE
#define IDX_OFF  (QE_SIZE + 1)

// ws layout (bytes)
// B2 is HI-ONLY: score = x·e_hi (2 MFMA products); dropped x·e_lo term has
// std ~0.018, covered by the top-3 fp64 rescue in finalize.
// hn[k] = -(0.5*||e_k||^2 + 256): acc-init value. The -256 bias makes every
// score strictly negative (Cauchy-Schwarz: s <= 0.5||x||^2 < 256 w.p. ~1),
// so the packed key is just (~bits & mask) | inv_code — 2 VALU ops to build.
// pk1/pk2: packed top-2 keys per (quarter, token):
//   key = (~float_bits(score) & 0xFFFFF800) | (2047 - local_code)
//   (monotone: bigger key = better score, ties -> smaller code index)
#define B2_OFF     0ULL                              // ushort B2[8192][256] (hi)
#define HN_OFF     (B2_OFF + 8192ULL*256*2)          // float hn[8192]
#define PK1_OFF    (HN_OFF + 8192ULL*4)              // uint pk1[4][16384]
#define PK2_OFF    (PK1_OFF + 4ULL*16384*4)          // uint pk2[4][16384]

typedef __attribute__((ext_vector_type(8))) short   bf16x8;
typedef __attribute__((ext_vector_type(8))) unsigned short ushort8v;
typedef __attribute__((ext_vector_type(4))) float   f32x4;

__device__ __forceinline__ void gld16(const void* g, void* l) {
    __builtin_amdgcn_global_load_lds(
        (const __attribute__((address_space(1))) void*)g,
        (__attribute__((address_space(3))) void*)l, 16, 0, 0);
}

// round-to-nearest-even fp32 -> bf16 bits
__device__ __forceinline__ unsigned short bf16_rn(float v) {
    uint32_t u = __float_as_uint(v);
    return (unsigned short)((u + 0x7fffu + ((u >> 16) & 1u)) >> 16);
}

// insert candidate (k, g) into running top-3 (key desc, idx asc on ties)
__device__ __forceinline__ void top3k_insert(unsigned& s1, int& i1,
                                             unsigned& s2, int& i2,
                                             unsigned& s3, int& i3,
                                             unsigned k, int g) {
    if (k > s1 || (k == s1 && g < i1)) {
        s3 = s2; i3 = i2; s2 = s1; i2 = i1; s1 = k; i1 = g;
    } else if (k > s2 || (k == s2 && g < i2)) {
        s3 = s2; i3 = i2; s2 = k; i2 = g;
    } else if (k > s3 || (k == s3 && g < i3)) {
        s3 = k; i3 = g;
    }
}

// ---------------------------------------------------------------------------
// Prep 1: split x -> A-FRAGMENT-MAJOR layout in d_out's qe region (16 MiB).
// LDS tile XOR-swizzled: (c, tok) lives at xt[c*64 + (tok ^ ((c>>3)&31))].
// ---------------------------------------------------------------------------
__global__ __launch_bounds__(256) void split_x_kernel(const float* __restrict__ x,
                                                      unsigned short* __restrict__ A) {
    __shared__ float xt[256 * 64];      // 64 KB, swizzled [c][tok]
    const int t = threadIdx.x;
    const int n0 = blockIdx.x * 64;
    const int b = n0 >> 10, hw0 = n0 & 1023;
    const int tok_l = t & 63, cg = t >> 6;
    const float* xb = x + ((size_t)b << 18) + hw0 + tok_l;
    #pragma unroll 8
    for (int i = 0; i < 64; ++i) {
        const int c = cg * 64 + i;
        xt[c * 64 + (tok_l ^ ((c >> 3) & 31))] = xb[(size_t)c << 10];
    }
    __syncthreads();
    const int tokq = t >> 5;            // 8 tokens per pass
    const int c8 = (t & 31) * 8;
    const int sw = (c8 >> 3) & 31;      // swizzle, uniform over u
    const int ksh = c8 >> 5;            // hi ks
    const int lq  = (c8 >> 3) & 3;      // quad within frag
    for (int p = 0; p < 8; ++p) {
        int tk = p * 8 + tokq;
        const int tks = tk ^ sw;
        unsigned short hi[8], lo[8];
        #pragma unroll
        for (int u = 0; u < 8; ++u) {
            float v = xt[(c8 + u) * 64 + tks];
            unsigned short h = bf16_rn(v);
            float fh = __uint_as_float(((uint32_t)h) << 16);
            lo[u] = bf16_rn(v - fh);
            hi[u] = h;
        }
        const int n  = n0 + tk;
        const int tb = n >> 4;
        const int l  = (tk & 15) + 16 * lq;
        *(ushort8v*)(A + ((size_t)((tb * 16 + ksh)     * 64) + l) * 8) = *(ushort8v*)hi;
        *(ushort8v*)(A + ((size_t)((tb * 16 + 8 + ksh) * 64) + l) * 8) = *(ushort8v*)lo;
    }
}

// ---------------------------------------------------------------------------
// Prep 2: codebook [8192][256] -> B2[k][256] hi-only bf16 and
// hn[k] = -(0.5*||e_k||^2 + 256) (the GEMM acc-init value; see header).
// Also zeroes the loss accumulator.
// ---------------------------------------------------------------------------
__global__ __launch_bounds__(256) void split_cb_kernel(const float* __restrict__ cb,
                                                       unsigned short* __restrict__ B2,
                                                       float* __restrict__ hn,
                                                       float* __restrict__ loss) {
    if (blockIdx.x == 0 && threadIdx.x == 0) *loss = 0.f;
    const int t = threadIdx.x;
    const int code = blockIdx.x * 8 + (t >> 5);
    const int c8 = (t & 31) * 8;
    const float* cr = cb + (size_t)code * CCH + c8;
    float s = 0.f;
    unsigned short hi[8];
    #pragma unroll
    for (int u = 0; u < 8; ++u) {
        float v = cr[u];
        s += v * v;
        hi[u] = bf16_rn(v);
    }
    *(ushort8v*)(B2 + (size_t)code * 256 + c8) = *(ushort8v*)hi;
    #pragma unroll
    for (int off = 16; off; off >>= 1) s += __shfl_xor(s, off);
    if ((t & 31) == 0) hn[code] = -(0.5f * s + 256.0f);
}

// ---------------------------------------------------------------------------
// Main: bf16 MFMA GEMM, fused branchless TOP-2 of (x·e_hi - 0.5||e||^2).
// v5: stage = FULL 64-code N-tile (32 KB = 4 slabs), 2x32 KB ping-pong ->
// ONE barrier per nt (32 total vs 128). Prefetch for nt+1 is issued at the
// top of nt and drains at nt's end-of-body barrier: ~2500 cyc of flight,
// covering cold-HBM latency. Within-slab layout/swizzle identical to the
// proven 8 KB-stage version (bank conflicts = 0).
// Epilogue: scores pre-biased negative (acc init = hn = -(h+256)), so the
// ordered key is (~bits & 0xFFFFF800)|inv_code: v_not + v_and_or + min/max/
// max = 5 VALU per eval (was 9).
// ---------------------------------------------------------------------------
__global__ __launch_bounds__(256, 2) void vq_gemm_kernel(const unsigned short* __restrict__ A,
                                                         const unsigned short* __restrict__ B2,
                                                         const float* __restrict__ hn,
                                                         unsigned* __restrict__ pk1,
                                                         unsigned* __restrict__ pk2) {
    __shared__ unsigned short Bsm[2][4][4096];    // 2 x (4 slabs x 8 KB) ping-pong
    __shared__ float hn_sm[2048];                 // 8 KB, this quarter's acc-init

    const int t = threadIdx.x;
    const int lane = t & 63, wave = t >> 6;
    const int l15 = lane & 15, quad = lane >> 4;

    const int mblk = blockIdx.x & 127;        // 128 M-blocks of 128 tokens
    const int nq   = blockIdx.x >> 7;         // 4 code quarters
    const int codeQ = nq * 2048;

    // A fragments: 32 coalesced dwordx4 loads, resident for the whole kernel
    bf16x8 af[2][16];
    #pragma unroll
    for (int i = 0; i < 2; ++i) {
        const int tb = mblk * 8 + wave * 2 + i;   // 16-token tile id
        const unsigned short* Abase = A + ((size_t)(tb * 16) * 64 + lane) * 8;
        #pragma unroll
        for (int ks = 0; ks < 16; ++ks)
            af[i][ks] = *(const bf16x8*)(Abase + (size_t)ks * 64 * 8);
    }

    // hn quarter -> LDS (8 KB; 2 x 1 KB wave-instrs per wave)
    #pragma unroll
    for (int i = 0; i < 2; ++i) {
        const int boff = (wave * 2 + i) * 1024;               // wave-uniform LDS base
        gld16((const char*)(hn + codeQ) + boff + lane * 16,   // per-lane global
              (char*)hn_sm + boff);
    }

    // B staging geometry (global_load_lds: wave-uniform base + lane*16)
    const int srow = wave * 8 + (lane >> 3);          // + it*32
    const int sch  = (lane & 7) ^ (srow & 7);         // swizzled source chunk

    // stage a FULL nt (64 codes x 256 ch = 4 slabs x 8 KB) into buffer P
#define STAGE_NT(P, NT)                                                        \
    do {                                                                       \
        _Pragma("unroll")                                                      \
        for (int s_ = 0; s_ < 4; ++s_) {                                       \
            char* dst = (char*)Bsm[P][s_] + wave * 1024;                       \
            const size_t bOff = (size_t)(codeQ + (NT) * 64 + srow) * 256       \
                                + s_ * 64 + sch * 8;                           \
            _Pragma("unroll")                                                  \
            for (int it = 0; it < 2; ++it)                                     \
                gld16(B2 + bOff + (size_t)it * (32 * 256), dst + it * 4096);   \
        }                                                                      \
    } while (0)

    unsigned K1[2][4], K2[2][4];
    #pragma unroll
    for (int i = 0; i < 2; ++i)
        #pragma unroll
        for (int r = 0; r < 4; ++r) { K1[i][r] = 0u; K2[i][r] = 0u; }

    STAGE_NT(0, 0);                 // prologue prefetch (with hn loads in flight)
    __syncthreads();                // drains all prologue vmem, once

    #pragma unroll 1
    for (int nt = 0; nt < 32; ++nt) {
        // prefetch nt+1 into the other buffer; flies under this nt's compute
        if (nt + 1 < 32) STAGE_NT((nt + 1) & 1, nt + 1);

        // acc init = hn = -(0.5||e||^2 + 256): MFMA output IS the biased score
        const int hb = nt * 64 + l15;
        f32x4 acc[2][4];
        #pragma unroll
        for (int j = 0; j < 4; ++j) {
            const float nh = hn_sm[hb + j * 16];
            #pragma unroll
            for (int i = 0; i < 2; ++i) {
                f32x4 z = {nh, nh, nh, nh};
                acc[i][j] = z;
            }
        }

        #pragma unroll
        for (int st = 0; st < 4; ++st) {
            const char* bs = (const char*)Bsm[nt & 1][st];
            #pragma unroll
            for (int ks2 = 0; ks2 < 2; ++ks2) {
                bf16x8 bfr[4];
                #pragma unroll
                for (int j = 0; j < 4; ++j) {
                    const int rowB = j * 16 + l15;
                    const int cbk = ((quad ^ (rowB & 7)) ^ (ks2 << 2)) * 16;
                    bfr[j] = *(const bf16x8*)(bs + rowB * 128 + cbk);
                }
                const int ka = st * 2 + ks2;           // K-chunk 0..7
                #pragma unroll
                for (int i = 0; i < 2; ++i) {
                    #pragma unroll
                    for (int j = 0; j < 4; ++j)        // xh·eh
                        acc[i][j] = __builtin_amdgcn_mfma_f32_16x16x32_bf16(
                            af[i][ka], bfr[j], acc[i][j], 0, 0, 0);
                    #pragma unroll
                    for (int j = 0; j < 4; ++j)        // xl·eh
                        acc[i][j] = __builtin_amdgcn_mfma_f32_16x16x32_bf16(
                            af[i][8 + ka], bfr[j], acc[i][j], 0, 0, 0);
                }
            }
        }

        // epilogue: branchless packed-key top-2 (all scores negative)
        // key = (~bits & 0xFFFFF800) | (2047 - local_code)
        const int icb = 2047 - (nt * 64 + l15);
        #pragma unroll
        for (int j = 0; j < 4; ++j) {
            const unsigned ic = (unsigned)(icb - j * 16);
            #pragma unroll
            for (int i = 0; i < 2; ++i)
                #pragma unroll
                for (int r = 0; r < 4; ++r) {
                    const unsigned u = __float_as_uint(acc[i][j][r]);
                    const unsigned k = (~u & 0xFFFFF800u) | ic;
                    const unsigned lo = min(k, K1[i][r]);
                    K1[i][r] = max(k, K1[i][r]);
                    K2[i][r] = max(K2[i][r], lo);
                }
        }

        __syncthreads();   // all waves done reading buf[nt&1]; nt+1 staged
    }
#undef STAGE_NT

    // top-2 butterfly across the 16-lane col groups (same tokens)
    #pragma unroll
    for (int off = 1; off < 16; off <<= 1) {
        #pragma unroll
        for (int i = 0; i < 2; ++i)
            #pragma unroll
            for (int r = 0; r < 4; ++r) {
                const unsigned t1 = __shfl_xor(K1[i][r], off);
                const unsigned t2 = __shfl_xor(K2[i][r], off);
                const unsigned lo = min(K1[i][r], t1);
                K1[i][r] = max(K1[i][r], t1);
                K2[i][r] = max(max(K2[i][r], t2), lo);
            }
    }

    // l15==0 lanes hold finals for tokens mblk*128 + wave*32 + i*16 + quad*4 + r
    if (l15 == 0) {
        #pragma unroll
        for (int i = 0; i < 2; ++i)
            #pragma unroll
            for (int r = 0; r < 4; ++r) {
                const int tok = mblk * 128 + wave * 32 + i * 16 + quad * 4 + r;
                const int gi = nq * NN + tok;
                pk1[gi] = K1[i][r]; pk2[gi] = K2[i][r];
            }
    }
}

// ---------------------------------------------------------------------------
// Finalize v4 (transpose-fused, TOP-3 rescue over packed keys):
//   A) merge 8 per-quarter packed keys -> top-3 candidates (decode global idx)
//   B) stage x transposed (coalesced)
//   R) fp64 rescore of all 3 candidates, 4 threads/token
//   P) pick true min of the 3, idx write, one loss atomic per block
//   C) load chosen code rows row-contiguous into LDS
//   D) write qe coalesced
// ---------------------------------------------------------------------------
__global__ __launch_bounds__(256) void finalize_kernel(const float* __restrict__ x,
                                                       const float* __restrict__ cb,
                                                       const unsigned* __restrict__ pk1,
                                                       const unsigned* __restrict__ pk2,
                                                       float* __restrict__ qe,
                                                       float* __restrict__ idx_f,
                                                       float* __restrict__ loss) {
    __shared__ float  xt[256 * 65];     // [c][tok] transposed tile, 65-pad; reused for e rows
    __shared__ int    cnd[3][64], bsx[64];
    __shared__ double dp[3][4][64];     // [cand][cq][tok]

    const int t = threadIdx.x;
    const int n0 = blockIdx.x * 64;
    const int b = n0 >> 10, hw0 = n0 & 1023;
    const int tok_l = t & 63, cg = t >> 6;

    // Phase A: top-3 of the 8 per-quarter packed candidates (wave 0)
    if (t < 64) {
        unsigned s1 = 0u, s2 = 0u, s3 = 0u;
        int i1 = 0x7ffffff, i2 = 0x7ffffff, i3 = 0x7ffffff;
        const int n = n0 + t;
        #pragma unroll
        for (int q = 0; q < 4; ++q) {
            const unsigned ka = pk1[q * NN + n];
            const unsigned kb = pk2[q * NN + n];
            const int ga = q * 2048 + 2047 - (int)(ka & 2047u);
            const int gb = q * 2048 + 2047 - (int)(kb & 2047u);
            top3k_insert(s1, i1, s2, i2, s3, i3, ka, ga);
            top3k_insert(s1, i1, s2, i2, s3, i3, kb, gb);
        }
        cnd[0][t] = i1; cnd[1][t] = i2; cnd[2][t] = i3;
    }

    // Phase B: stage x transposed, fully coalesced (lane = hw)
    const float* xb = x + ((size_t)b << 18) + hw0 + tok_l;
    #pragma unroll 8
    for (int i = 0; i < 64; ++i) {
        const int c = cg * 64 + i;
        xt[c * 65 + tok_l] = xb[(size_t)c << 10];
    }
    __syncthreads();

    // Phase R: fp64 rescore of the 3 candidates; 4 threads per token
    {
        const int tok = t & 63, cq = t >> 6;
        const float* c0 = cb + (size_t)cnd[0][tok] * CCH + cq * 64;
        const float* c1 = cb + (size_t)cnd[1][tok] * CCH + cq * 64;
        const float* c2 = cb + (size_t)cnd[2][tok] * CCH + cq * 64;
        double d0 = 0.0, d1 = 0.0, d2 = 0.0;
        #pragma unroll
        for (int j = 0; j < 64; j += 4) {
            const f32x4 e0 = *(const f32x4*)(c0 + j);
            const f32x4 e1 = *(const f32x4*)(c1 + j);
            const f32x4 e2 = *(const f32x4*)(c2 + j);
            #pragma unroll
            for (int u = 0; u < 4; ++u) {
                const float xv = xt[(cq * 64 + j + u) * 65 + tok];
                const double dx0 = (double)xv - (double)e0[u];
                const double dx1 = (double)xv - (double)e1[u];
                const double dx2 = (double)xv - (double)e2[u];
                d0 += dx0 * dx0;
                d1 += dx1 * dx1;
                d2 += dx2 * dx2;
            }
        }
        dp[0][cq][tok] = d0; dp[1][cq][tok] = d1; dp[2][cq][tok] = d2;
    }
    __syncthreads();

    // Phase P: pick true min of the 3 per token (wave 0), idx, loss atomic
    if (t < 64) {
        double dd[3]; int ii[3];
        #pragma unroll
        for (int c = 0; c < 3; ++c) {
            dd[c] = dp[c][0][t] + dp[c][1][t] + dp[c][2][t] + dp[c][3][t];
            ii[c] = cnd[c][t];
        }
        int bi = ii[0]; double bd = dd[0];
        if (dd[1] < bd || (dd[1] == bd && ii[1] < bi)) { bd = dd[1]; bi = ii[1]; }
        if (dd[2] < bd || (dd[2] == bd && ii[2] < bi)) { bd = dd[2]; bi = ii[2]; }
        bsx[t] = bi;
        idx_f[n0 + t] = (float)bi;
        float lsum = (float)bd;
        #pragma unroll
        for (int off = 32; off; off >>= 1) lsum += __shfl_down(lsum, off);
        if (t == 0) atomicAdd(loss, lsum * (1.0f / ((float)NN * (float)CCH)));
    }
    __syncthreads();

    // Phase C: load chosen code rows (row-contiguous, coalesced) into xt
    {
        const int w = t >> 6, lane = t & 63;
        #pragma unroll 4
        for (int i = 0; i < 16; ++i) {
            const int tok = w * 16 + i;
            const float* e = cb + (size_t)bsx[tok] * CCH;
            #pragma unroll
            for (int u = 0; u < 4; ++u) {
                const int c = u * 64 + lane;
                xt[c * 65 + tok] = e[c];
            }
        }
    }
    __syncthreads();

    // Phase D: write qe coalesced from the transposed LDS (lane = hw)
    float* qb = qe + ((size_t)b << 18) + hw0 + tok_l;
    #pragma unroll 8
    for (int i = 0; i < 64; ++i) {
        const int c = cg * 64 + i;
        qb[(size_t)c << 10] = xt[c * 65 + tok_l];
    }
}

// ---------------------------------------------------------------------------
extern "C" void kernel_launch(void* const* d_in, const int* in_sizes, int n_in,
                              void* d_out, int out_size, void* d_ws, size_t ws_size,
                              hipStream_t stream) {
    const float* x  = (const float*)d_in[0];
    const float* cb = (const float*)d_in[1];
    float* out = (float*)d_out;
    char* ws = (char*)d_ws;

    // A (frag-major) lives in d_out's qe region (16 MiB); finalize rewrites qe.
    unsigned short* A  = (unsigned short*)out;
    unsigned short* B2 = (unsigned short*)(ws + B2_OFF);
    float* hn  = (float*)(ws + HN_OFF);
    unsigned* pk1 = (unsigned*)(ws + PK1_OFF);
    unsigned* pk2 = (unsigned*)(ws + PK2_OFF);

    split_x_kernel <<<NN / 64, 256, 0, stream>>>(x, A);
    split_cb_kernel<<<KK / 8, 256, 0, stream>>>(cb, B2, hn, out + LOSS_OFF);
    vq_gemm_kernel <<<512, 256, 0, stream>>>(A, B2, hn, pk1, pk2);
    finalize_kernel<<<NN / 64, 256, 0, stream>>>(x, cb, pk1, pk2,
                                                 out, out + IDX_OFF,
                                                 out + LOSS_OFF);
}

// Round 6
// 198.729 us; speedup vs baseline: 1.7129x; 1.0233x over previous
//
#include <hip/hip_runtime.h>
#include <hip/hip_bf16.h>
#include <stdint.h>

// Problem constants
#define KK   8192
#define NN   16384      // B*H*W tokens
#define CCH  256        // channels

#define QE_SIZE  4194304            // NN*CCH floats
#define LOSS_OFF QE_SIZE
#define IDX_OFF  (QE_SIZE + 1)

// ws layout (bytes)
// B2 is HI-ONLY: score = x·e_hi (2 MFMA products); dropped x·e_lo term has
// std ~0.018, covered by the top-3 fp64 rescue in finalize.
// hn[k] = -(0.5*||e_k||^2 + 256): acc-init value. The -256 bias makes every
// score strictly negative (Cauchy-Schwarz: s <= 0.5||x||^2 < 256 w.p. ~1),
// so the packed key is just (~bits & mask) | inv_code — 2 VALU ops to build.
// pk1/pk2: packed top-2 keys per (quarter, token):
//   key = (~float_bits(score) & 0xFFFFF800) | (2047 - local_code)
//   (monotone: bigger key = better score, ties -> smaller code index)
#define B2_OFF     0ULL                              // ushort B2[8192][256] (hi)
#define HN_OFF     (B2_OFF + 8192ULL*256*2)          // float hn[8192]
#define PK1_OFF    (HN_OFF + 8192ULL*4)              // uint pk1[4][16384]
#define PK2_OFF    (PK1_OFF + 4ULL*16384*4)          // uint pk2[4][16384]

typedef __attribute__((ext_vector_type(8))) short   bf16x8;
typedef __attribute__((ext_vector_type(8))) unsigned short ushort8v;
typedef __attribute__((ext_vector_type(4))) float   f32x4;

__device__ __forceinline__ void gld16(const void* g, void* l) {
    __builtin_amdgcn_global_load_lds(
        (const __attribute__((address_space(1))) void*)g,
        (__attribute__((address_space(3))) void*)l, 16, 0, 0);
}

// round-to-nearest-even fp32 -> bf16 bits
__device__ __forceinline__ unsigned short bf16_rn(float v) {
    uint32_t u = __float_as_uint(v);
    return (unsigned short)((u + 0x7fffu + ((u >> 16) & 1u)) >> 16);
}

// insert candidate (k, g) into running top-3 (key desc, idx asc on ties)
__device__ __forceinline__ void top3k_insert(unsigned& s1, int& i1,
                                             unsigned& s2, int& i2,
                                             unsigned& s3, int& i3,
                                             unsigned k, int g) {
    if (k > s1 || (k == s1 && g < i1)) {
        s3 = s2; i3 = i2; s2 = s1; i2 = i1; s1 = k; i1 = g;
    } else if (k > s2 || (k == s2 && g < i2)) {
        s3 = s2; i3 = i2; s2 = k; i2 = g;
    } else if (k > s3 || (k == s3 && g < i3)) {
        s3 = k; i3 = g;
    }
}

// ---------------------------------------------------------------------------
// Fused prep (one launch): blocks 0..255 = split_x tiles, 256..1279 = codebook.
//
// split_x part: x -> A-FRAGMENT-MAJOR layout in d_out's qe region (16 MiB).
// LDS tile XOR-swizzled: (c, tok) lives at xt[c*64 + (tok ^ ((c>>3)&31))].
//
// codebook part: cb[8192][256] -> B2[k][256] hi-only bf16 and
// hn[k] = -(0.5*||e_k||^2 + 256) (GEMM acc-init; see header). Block 256
// thread 0 also zeroes the loss accumulator.
// ---------------------------------------------------------------------------
__global__ __launch_bounds__(256) void prep_kernel(const float* __restrict__ x,
                                                   const float* __restrict__ cb,
                                                   unsigned short* __restrict__ A,
                                                   unsigned short* __restrict__ B2,
                                                   float* __restrict__ hn,
                                                   float* __restrict__ loss) {
    __shared__ float xt[256 * 64];      // 64 KB, swizzled [c][tok] (x-path only)
    const int t = threadIdx.x;
    const int bid = blockIdx.x;

    if (bid >= 256) {
        // ---- codebook path (no barriers) ----
        const int cbid = bid - 256;
        if (cbid == 0 && t == 0) *loss = 0.f;
        const int code = cbid * 8 + (t >> 5);
        const int c8 = (t & 31) * 8;
        const float* cr = cb + (size_t)code * CCH + c8;
        float s = 0.f;
        unsigned short hi[8];
        #pragma unroll
        for (int u = 0; u < 8; ++u) {
            float v = cr[u];
            s += v * v;
            hi[u] = bf16_rn(v);
        }
        *(ushort8v*)(B2 + (size_t)code * 256 + c8) = *(ushort8v*)hi;
        #pragma unroll
        for (int off = 16; off; off >>= 1) s += __shfl_xor(s, off);
        if ((t & 31) == 0) hn[code] = -(0.5f * s + 256.0f);
        return;
    }

    // ---- x path ----
    const int n0 = bid * 64;
    const int b = n0 >> 10, hw0 = n0 & 1023;
    const int tok_l = t & 63, cg = t >> 6;
    const float* xb = x + ((size_t)b << 18) + hw0 + tok_l;
    #pragma unroll 8
    for (int i = 0; i < 64; ++i) {
        const int c = cg * 64 + i;
        xt[c * 64 + (tok_l ^ ((c >> 3) & 31))] = xb[(size_t)c << 10];
    }
    __syncthreads();
    const int tokq = t >> 5;            // 8 tokens per pass
    const int c8 = (t & 31) * 8;
    const int sw = (c8 >> 3) & 31;      // swizzle, uniform over u
    const int ksh = c8 >> 5;            // hi ks
    const int lq  = (c8 >> 3) & 3;      // quad within frag
    for (int p = 0; p < 8; ++p) {
        int tk = p * 8 + tokq;
        const int tks = tk ^ sw;
        unsigned short hi[8], lo[8];
        #pragma unroll
        for (int u = 0; u < 8; ++u) {
            float v = xt[(c8 + u) * 64 + tks];
            unsigned short h = bf16_rn(v);
            float fh = __uint_as_float(((uint32_t)h) << 16);
            lo[u] = bf16_rn(v - fh);
            hi[u] = h;
        }
        const int n  = n0 + tk;
        const int tb = n >> 4;
        const int l  = (tk & 15) + 16 * lq;
        *(ushort8v*)(A + ((size_t)((tb * 16 + ksh)     * 64) + l) * 8) = *(ushort8v*)hi;
        *(ushort8v*)(A + ((size_t)((tb * 16 + 8 + ksh) * 64) + l) * 8) = *(ushort8v*)lo;
    }
}

// ---------------------------------------------------------------------------
// Main: bf16 MFMA GEMM, fused branchless TOP-2 of (x·e_hi - 0.5||e||^2).
// v5 (validated R5: 112 µs, MfmaUtil 55%): stage = FULL 64-code N-tile
// (32 KB = 4 slabs), 2x32 KB ping-pong -> ONE barrier per nt. Epilogue:
// scores pre-biased negative (acc init = hn), packed key = (~bits & mask) |
// inv_code: 5 VALU per eval. UNCHANGED this round.
// ---------------------------------------------------------------------------
__global__ __launch_bounds__(256, 2) void vq_gemm_kernel(const unsigned short* __restrict__ A,
                                                         const unsigned short* __restrict__ B2,
                                                         const float* __restrict__ hn,
                                                         unsigned* __restrict__ pk1,
                                                         unsigned* __restrict__ pk2) {
    __shared__ unsigned short Bsm[2][4][4096];    // 2 x (4 slabs x 8 KB) ping-pong
    __shared__ float hn_sm[2048];                 // 8 KB, this quarter's acc-init

    const int t = threadIdx.x;
    const int lane = t & 63, wave = t >> 6;
    const int l15 = lane & 15, quad = lane >> 4;

    const int mblk = blockIdx.x & 127;        // 128 M-blocks of 128 tokens
    const int nq   = blockIdx.x >> 7;         // 4 code quarters
    const int codeQ = nq * 2048;

    // A fragments: 32 coalesced dwordx4 loads, resident for the whole kernel
    bf16x8 af[2][16];
    #pragma unroll
    for (int i = 0; i < 2; ++i) {
        const int tb = mblk * 8 + wave * 2 + i;   // 16-token tile id
        const unsigned short* Abase = A + ((size_t)(tb * 16) * 64 + lane) * 8;
        #pragma unroll
        for (int ks = 0; ks < 16; ++ks)
            af[i][ks] = *(const bf16x8*)(Abase + (size_t)ks * 64 * 8);
    }

    // hn quarter -> LDS (8 KB; 2 x 1 KB wave-instrs per wave)
    #pragma unroll
    for (int i = 0; i < 2; ++i) {
        const int boff = (wave * 2 + i) * 1024;               // wave-uniform LDS base
        gld16((const char*)(hn + codeQ) + boff + lane * 16,   // per-lane global
              (char*)hn_sm + boff);
    }

    // B staging geometry (global_load_lds: wave-uniform base + lane*16)
    const int srow = wave * 8 + (lane >> 3);          // + it*32
    const int sch  = (lane & 7) ^ (srow & 7);         // swizzled source chunk

    // stage a FULL nt (64 codes x 256 ch = 4 slabs x 8 KB) into buffer P
#define STAGE_NT(P, NT)                                                        \
    do {                                                                       \
        _Pragma("unroll")                                                      \
        for (int s_ = 0; s_ < 4; ++s_) {                                       \
            char* dst = (char*)Bsm[P][s_] + wave * 1024;                       \
            const size_t bOff = (size_t)(codeQ + (NT) * 64 + srow) * 256       \
                                + s_ * 64 + sch * 8;                           \
            _Pragma("unroll")                                                  \
            for (int it = 0; it < 2; ++it)                                     \
                gld16(B2 + bOff + (size_t)it * (32 * 256), dst + it * 4096);   \
        }                                                                      \
    } while (0)

    unsigned K1[2][4], K2[2][4];
    #pragma unroll
    for (int i = 0; i < 2; ++i)
        #pragma unroll
        for (int r = 0; r < 4; ++r) { K1[i][r] = 0u; K2[i][r] = 0u; }

    STAGE_NT(0, 0);                 // prologue prefetch (with hn loads in flight)
    __syncthreads();                // drains all prologue vmem, once

    #pragma unroll 1
    for (int nt = 0; nt < 32; ++nt) {
        // prefetch nt+1 into the other buffer; flies under this nt's compute
        if (nt + 1 < 32) STAGE_NT((nt + 1) & 1, nt + 1);

        // acc init = hn = -(0.5||e||^2 + 256): MFMA output IS the biased score
        const int hb = nt * 64 + l15;
        f32x4 acc[2][4];
        #pragma unroll
        for (int j = 0; j < 4; ++j) {
            const float nh = hn_sm[hb + j * 16];
            #pragma unroll
            for (int i = 0; i < 2; ++i) {
                f32x4 z = {nh, nh, nh, nh};
                acc[i][j] = z;
            }
        }

        #pragma unroll
        for (int st = 0; st < 4; ++st) {
            const char* bs = (const char*)Bsm[nt & 1][st];
            #pragma unroll
            for (int ks2 = 0; ks2 < 2; ++ks2) {
                bf16x8 bfr[4];
                #pragma unroll
                for (int j = 0; j < 4; ++j) {
                    const int rowB = j * 16 + l15;
                    const int cbk = ((quad ^ (rowB & 7)) ^ (ks2 << 2)) * 16;
                    bfr[j] = *(const bf16x8*)(bs + rowB * 128 + cbk);
                }
                const int ka = st * 2 + ks2;           // K-chunk 0..7
                #pragma unroll
                for (int i = 0; i < 2; ++i) {
                    #pragma unroll
                    for (int j = 0; j < 4; ++j)        // xh·eh
                        acc[i][j] = __builtin_amdgcn_mfma_f32_16x16x32_bf16(
                            af[i][ka], bfr[j], acc[i][j], 0, 0, 0);
                    #pragma unroll
                    for (int j = 0; j < 4; ++j)        // xl·eh
                        acc[i][j] = __builtin_amdgcn_mfma_f32_16x16x32_bf16(
                            af[i][8 + ka], bfr[j], acc[i][j], 0, 0, 0);
                }
            }
        }

        // epilogue: branchless packed-key top-2 (all scores negative)
        // key = (~bits & 0xFFFFF800) | (2047 - local_code)
        const int icb = 2047 - (nt * 64 + l15);
        #pragma unroll
        for (int j = 0; j < 4; ++j) {
            const unsigned ic = (unsigned)(icb - j * 16);
            #pragma unroll
            for (int i = 0; i < 2; ++i)
                #pragma unroll
                for (int r = 0; r < 4; ++r) {
                    const unsigned u = __float_as_uint(acc[i][j][r]);
                    const unsigned k = (~u & 0xFFFFF800u) | ic;
                    const unsigned lo = min(k, K1[i][r]);
                    K1[i][r] = max(k, K1[i][r]);
                    K2[i][r] = max(K2[i][r], lo);
                }
        }

        __syncthreads();   // all waves done reading buf[nt&1]; nt+1 staged
    }
#undef STAGE_NT

    // top-2 butterfly across the 16-lane col groups (same tokens)
    #pragma unroll
    for (int off = 1; off < 16; off <<= 1) {
        #pragma unroll
        for (int i = 0; i < 2; ++i)
            #pragma unroll
            for (int r = 0; r < 4; ++r) {
                const unsigned t1 = __shfl_xor(K1[i][r], off);
                const unsigned t2 = __shfl_xor(K2[i][r], off);
                const unsigned lo = min(K1[i][r], t1);
                K1[i][r] = max(K1[i][r], t1);
                K2[i][r] = max(max(K2[i][r], t2), lo);
            }
    }

    // l15==0 lanes hold finals for tokens mblk*128 + wave*32 + i*16 + quad*4 + r
    if (l15 == 0) {
        #pragma unroll
        for (int i = 0; i < 2; ++i)
            #pragma unroll
            for (int r = 0; r < 4; ++r) {
                const int tok = mblk * 128 + wave * 32 + i * 16 + quad * 4 + r;
                const int gi = nq * NN + tok;
                pk1[gi] = K1[i][r]; pk2[gi] = K2[i][r];
            }
    }
}

// ---------------------------------------------------------------------------
// Finalize v5: 512 threads/block (8 waves/CU — was 4: every phase was
// latency-exposed at 1 block/CU). Same algorithm as v4:
//   A) merge 8 per-quarter packed keys -> top-3 candidates (wave 0)
//   B) stage x transposed, 8 channel-groups of 32 (coalesced)
//   R) fp64 rescore of 3 candidates, 8 threads/token (32 ch each)
//   P) pick true min of 3 (wave 0), idx write, one loss atomic
//   C) load chosen code rows row-contiguous (8 waves x 8 tokens)
//   D) write qe coalesced
// ---------------------------------------------------------------------------
__global__ __launch_bounds__(512) void finalize_kernel(const float* __restrict__ x,
                                                       const float* __restrict__ cb,
                                                       const unsigned* __restrict__ pk1,
                                                       const unsigned* __restrict__ pk2,
                                                       float* __restrict__ qe,
                                                       float* __restrict__ idx_f,
                                                       float* __restrict__ loss) {
    __shared__ float  xt[256 * 65];     // [c][tok] transposed tile, 65-pad; reused for e rows
    __shared__ int    cnd[3][64], bsx[64];
    __shared__ double dp[3][8][64];     // [cand][cq][tok]

    const int t = threadIdx.x;
    const int n0 = blockIdx.x * 64;
    const int b = n0 >> 10, hw0 = n0 & 1023;
    const int tok_l = t & 63, cg = t >> 6;      // cg in [0,8)

    // Phase A: top-3 of the 8 per-quarter packed candidates (wave 0)
    if (t < 64) {
        unsigned s1 = 0u, s2 = 0u, s3 = 0u;
        int i1 = 0x7ffffff, i2 = 0x7ffffff, i3 = 0x7ffffff;
        const int n = n0 + t;
        #pragma unroll
        for (int q = 0; q < 4; ++q) {
            const unsigned ka = pk1[q * NN + n];
            const unsigned kb = pk2[q * NN + n];
            const int ga = q * 2048 + 2047 - (int)(ka & 2047u);
            const int gb = q * 2048 + 2047 - (int)(kb & 2047u);
            top3k_insert(s1, i1, s2, i2, s3, i3, ka, ga);
            top3k_insert(s1, i1, s2, i2, s3, i3, kb, gb);
        }
        cnd[0][t] = i1; cnd[1][t] = i2; cnd[2][t] = i3;
    }

    // Phase B: stage x transposed, fully coalesced (lane = hw); 32 ch/group
    const float* xb = x + ((size_t)b << 18) + hw0 + tok_l;
    #pragma unroll 8
    for (int i = 0; i < 32; ++i) {
        const int c = cg * 32 + i;
        xt[c * 65 + tok_l] = xb[(size_t)c << 10];
    }
    __syncthreads();

    // Phase R: fp64 rescore of the 3 candidates; 8 threads per token
    {
        const int tok = t & 63, cq = t >> 6;
        const float* c0 = cb + (size_t)cnd[0][tok] * CCH + cq * 32;
        const float* c1 = cb + (size_t)cnd[1][tok] * CCH + cq * 32;
        const float* c2 = cb + (size_t)cnd[2][tok] * CCH + cq * 32;
        double d0 = 0.0, d1 = 0.0, d2 = 0.0;
        #pragma unroll
        for (int j = 0; j < 32; j += 4) {
            const f32x4 e0 = *(const f32x4*)(c0 + j);
            const f32x4 e1 = *(const f32x4*)(c1 + j);
            const f32x4 e2 = *(const f32x4*)(c2 + j);
            #pragma unroll
            for (int u = 0; u < 4; ++u) {
                const float xv = xt[(cq * 32 + j + u) * 65 + tok];
                const double dx0 = (double)xv - (double)e0[u];
                const double dx1 = (double)xv - (double)e1[u];
                const double dx2 = (double)xv - (double)e2[u];
                d0 += dx0 * dx0;
                d1 += dx1 * dx1;
                d2 += dx2 * dx2;
            }
        }
        dp[0][cq][tok] = d0; dp[1][cq][tok] = d1; dp[2][cq][tok] = d2;
    }
    __syncthreads();

    // Phase P: pick true min of the 3 per token (wave 0), idx, loss atomic
    if (t < 64) {
        double dd[3]; int ii[3];
        #pragma unroll
        for (int c = 0; c < 3; ++c) {
            double s = 0.0;
            #pragma unroll
            for (int q = 0; q < 8; ++q) s += dp[c][q][t];
            dd[c] = s;
            ii[c] = cnd[c][t];
        }
        int bi = ii[0]; double bd = dd[0];
        if (dd[1] < bd || (dd[1] == bd && ii[1] < bi)) { bd = dd[1]; bi = ii[1]; }
        if (dd[2] < bd || (dd[2] == bd && ii[2] < bi)) { bd = dd[2]; bi = ii[2]; }
        bsx[t] = bi;
        idx_f[n0 + t] = (float)bi;
        float lsum = (float)bd;
        #pragma unroll
        for (int off = 32; off; off >>= 1) lsum += __shfl_down(lsum, off);
        if (t == 0) atomicAdd(loss, lsum * (1.0f / ((float)NN * (float)CCH)));
    }
    __syncthreads();

    // Phase C: load chosen code rows (row-contiguous, coalesced) into xt
    {
        const int w = t >> 6, lane = t & 63;     // 8 waves x 8 tokens
        #pragma unroll
        for (int i = 0; i < 8; ++i) {
            const int tok = w * 8 + i;
            const float* e = cb + (size_t)bsx[tok] * CCH;
            #pragma unroll
            for (int u = 0; u < 4; ++u) {
                const int c = u * 64 + lane;
                xt[c * 65 + tok] = e[c];
            }
        }
    }
    __syncthreads();

    // Phase D: write qe coalesced from the transposed LDS (lane = hw)
    float* qb = qe + ((size_t)b << 18) + hw0 + tok_l;
    #pragma unroll 8
    for (int i = 0; i < 32; ++i) {
        const int c = cg * 32 + i;
        qb[(size_t)c << 10] = xt[c * 65 + tok_l];
    }
}

// ---------------------------------------------------------------------------
extern "C" void kernel_launch(void* const* d_in, const int* in_sizes, int n_in,
                              void* d_out, int out_size, void* d_ws, size_t ws_size,
                              hipStream_t stream) {
    const float* x  = (const float*)d_in[0];
    const float* cb = (const float*)d_in[1];
    float* out = (float*)d_out;
    char* ws = (char*)d_ws;

    // A (frag-major) lives in d_out's qe region (16 MiB); finalize rewrites qe.
    unsigned short* A  = (unsigned short*)out;
    unsigned short* B2 = (unsigned short*)(ws + B2_OFF);
    float* hn  = (float*)(ws + HN_OFF);
    unsigned* pk1 = (unsigned*)(ws + PK1_OFF);
    unsigned* pk2 = (unsigned*)(ws + PK2_OFF);

    prep_kernel    <<<256 + KK / 8, 256, 0, stream>>>(x, cb, A, B2, hn,
                                                      out + LOSS_OFF);
    vq_gemm_kernel <<<512, 256, 0, stream>>>(A, B2, hn, pk1, pk2);
    finalize_kernel<<<NN / 64, 512, 0, stream>>>(x, cb, pk1, pk2,
                                                 out, out + IDX_OFF,
                                                 out + LOSS_OFF);
}

// Round 7
// 165.546 us; speedup vs baseline: 2.0562x; 1.2004x over previous
//
#include <hip/hip_runtime.h>
#include <hip/hip_bf16.h>
#include <stdint.h>

// Problem constants
#define KK   8192
#define NN   16384      // B*H*W tokens
#define CCH  256        // channels

#define QE_SIZE  4194304            // NN*CCH floats
#define LOSS_OFF QE_SIZE
#define IDX_OFF  (QE_SIZE + 1)

// ws layout (bytes)
// SINGLE-PRODUCT GEMM: score = bf16(x)·bf16(e) - 0.5||e||^2 - 256.
// Quantization error sigma ~0.025 (x-side + e-side) + 0.06 key truncation,
// vs top-rank score gaps ~3.8: the fp64 top-3 rescue in finalize recovers
// the exact argmin (it rescores with exact fp32 x and cb).
// hn[k] = -(0.5*||e_k||^2 + 256): acc-init value. The -256 bias makes every
// score strictly negative (0.5||x||^2 < 256 w.p. ~1), so the packed key is
// (~bits & mask) | inv_code — 2 VALU ops to build.
// pk1/pk2: packed top-2 keys per (quarter, token):
//   key = (~float_bits(score) & 0xFFFFF800) | (2047 - local_code)
//   (monotone: bigger key = better score, ties -> smaller code index)
#define B2_OFF     0ULL                              // ushort B2[8192][256] (hi)
#define HN_OFF     (B2_OFF + 8192ULL*256*2)          // float hn[8192]
#define PK1_OFF    (HN_OFF + 8192ULL*4)              // uint pk1[4][16384]
#define PK2_OFF    (PK1_OFF + 4ULL*16384*4)          // uint pk2[4][16384]

typedef __attribute__((ext_vector_type(8))) short   bf16x8;
typedef __attribute__((ext_vector_type(8))) unsigned short ushort8v;
typedef __attribute__((ext_vector_type(4))) float   f32x4;

__device__ __forceinline__ void gld16(const void* g, void* l) {
    __builtin_amdgcn_global_load_lds(
        (const __attribute__((address_space(1))) void*)g,
        (__attribute__((address_space(3))) void*)l, 16, 0, 0);
}

// round-to-nearest-even fp32 -> bf16 bits
__device__ __forceinline__ unsigned short bf16_rn(float v) {
    uint32_t u = __float_as_uint(v);
    return (unsigned short)((u + 0x7fffu + ((u >> 16) & 1u)) >> 16);
}

// insert candidate (k, g) into running top-3 (key desc, idx asc on ties)
__device__ __forceinline__ void top3k_insert(unsigned& s1, int& i1,
                                             unsigned& s2, int& i2,
                                             unsigned& s3, int& i3,
                                             unsigned k, int g) {
    if (k > s1 || (k == s1 && g < i1)) {
        s3 = s2; i3 = i2; s2 = s1; i2 = i1; s1 = k; i1 = g;
    } else if (k > s2 || (k == s2 && g < i2)) {
        s3 = s2; i3 = i2; s2 = k; i2 = g;
    } else if (k > s3 || (k == s3 && g < i3)) {
        s3 = k; i3 = g;
    }
}

// ---------------------------------------------------------------------------
// Fused prep (one launch): blocks 0..255 = split_x tiles, 256..1279 = codebook.
//
// split_x part: x -> A-FRAGMENT-MAJOR bf16 (HI ONLY now) in d_out's qe
// region. For 16-token tile tb, k-step ks (0..7), lane l: 8 bf16 of token
// tb*16+(l&15), channels ks*32 + (l>>4)*8. Addr = ((tb*8 + ks)*64 + l)*8.
// LDS tile XOR-swizzled: (c, tok) lives at xt[c*64 + (tok ^ ((c>>3)&31))].
//
// codebook part: cb[8192][256] -> B2[k][256] hi-only bf16 and
// hn[k] = -(0.5*||e_k||^2 + 256) (GEMM acc-init; see header). Block 256
// thread 0 also zeroes the loss accumulator.
// ---------------------------------------------------------------------------
__global__ __launch_bounds__(256) void prep_kernel(const float* __restrict__ x,
                                                   const float* __restrict__ cb,
                                                   unsigned short* __restrict__ A,
                                                   unsigned short* __restrict__ B2,
                                                   float* __restrict__ hn,
                                                   float* __restrict__ loss) {
    __shared__ float xt[256 * 64];      // 64 KB, swizzled [c][tok] (x-path only)
    const int t = threadIdx.x;
    const int bid = blockIdx.x;

    if (bid >= 256) {
        // ---- codebook path (no barriers) ----
        const int cbid = bid - 256;
        if (cbid == 0 && t == 0) *loss = 0.f;
        const int code = cbid * 8 + (t >> 5);
        const int c8 = (t & 31) * 8;
        const float* cr = cb + (size_t)code * CCH + c8;
        float s = 0.f;
        unsigned short hi[8];
        #pragma unroll
        for (int u = 0; u < 8; ++u) {
            float v = cr[u];
            s += v * v;
            hi[u] = bf16_rn(v);
        }
        *(ushort8v*)(B2 + (size_t)code * 256 + c8) = *(ushort8v*)hi;
        #pragma unroll
        for (int off = 16; off; off >>= 1) s += __shfl_xor(s, off);
        if ((t & 31) == 0) hn[code] = -(0.5f * s + 256.0f);
        return;
    }

    // ---- x path ----
    const int n0 = bid * 64;
    const int b = n0 >> 10, hw0 = n0 & 1023;
    const int tok_l = t & 63, cg = t >> 6;
    const float* xb = x + ((size_t)b << 18) + hw0 + tok_l;
    #pragma unroll 8
    for (int i = 0; i < 64; ++i) {
        const int c = cg * 64 + i;
        xt[c * 64 + (tok_l ^ ((c >> 3) & 31))] = xb[(size_t)c << 10];
    }
    __syncthreads();
    const int tokq = t >> 5;            // 8 tokens per pass
    const int c8 = (t & 31) * 8;
    const int sw = (c8 >> 3) & 31;      // swizzle, uniform over u
    const int ksh = c8 >> 5;            // k-step
    const int lq  = (c8 >> 3) & 3;      // quad within frag
    for (int p = 0; p < 8; ++p) {
        int tk = p * 8 + tokq;
        const int tks = tk ^ sw;
        unsigned short hi[8];
        #pragma unroll
        for (int u = 0; u < 8; ++u)
            hi[u] = bf16_rn(xt[(c8 + u) * 64 + tks]);
        const int n  = n0 + tk;
        const int tb = n >> 4;
        const int l  = (tk & 15) + 16 * lq;
        *(ushort8v*)(A + ((size_t)((tb * 8 + ksh) * 64) + l) * 8) = *(ushort8v*)hi;
    }
}

// ---------------------------------------------------------------------------
// Main: bf16 MFMA GEMM, fused branchless TOP-2 of (x·e - 0.5||e||^2 - 256).
// v6: SINGLE product (bf16 x · bf16 e) — half the MFMA work of v5; the
// matrix pipe is no longer the longest (LDS-read ~3072 cyc/CU/nt, VALU
// ~3200, MFMA ~2483). Pipeline unchanged from validated v5: stage = FULL
// 64-code N-tile (32 KB = 4 slabs), 2x32 KB ping-pong, ONE barrier per nt.
// Epilogue: packed key = (~bits & 0xFFFFF800) | inv_code, 5 VALU per eval.
// ---------------------------------------------------------------------------
__global__ __launch_bounds__(256, 2) void vq_gemm_kernel(const unsigned short* __restrict__ A,
                                                         const unsigned short* __restrict__ B2,
                                                         const float* __restrict__ hn,
                                                         unsigned* __restrict__ pk1,
                                                         unsigned* __restrict__ pk2) {
    __shared__ unsigned short Bsm[2][4][4096];    // 2 x (4 slabs x 8 KB) ping-pong
    __shared__ float hn_sm[2048];                 // 8 KB, this quarter's acc-init

    const int t = threadIdx.x;
    const int lane = t & 63, wave = t >> 6;
    const int l15 = lane & 15, quad = lane >> 4;

    const int mblk = blockIdx.x & 127;        // 128 M-blocks of 128 tokens
    const int nq   = blockIdx.x >> 7;         // 4 code quarters
    const int codeQ = nq * 2048;

    // A fragments: 16 coalesced dwordx4 loads, resident for the whole kernel
    bf16x8 af[2][8];
    #pragma unroll
    for (int i = 0; i < 2; ++i) {
        const int tb = mblk * 8 + wave * 2 + i;   // 16-token tile id
        const unsigned short* Abase = A + ((size_t)(tb * 8) * 64 + lane) * 8;
        #pragma unroll
        for (int ks = 0; ks < 8; ++ks)
            af[i][ks] = *(const bf16x8*)(Abase + (size_t)ks * 64 * 8);
    }

    // hn quarter -> LDS (8 KB; 2 x 1 KB wave-instrs per wave)
    #pragma unroll
    for (int i = 0; i < 2; ++i) {
        const int boff = (wave * 2 + i) * 1024;               // wave-uniform LDS base
        gld16((const char*)(hn + codeQ) + boff + lane * 16,   // per-lane global
              (char*)hn_sm + boff);
    }

    // B staging geometry (global_load_lds: wave-uniform base + lane*16)
    const int srow = wave * 8 + (lane >> 3);          // + it*32
    const int sch  = (lane & 7) ^ (srow & 7);         // swizzled source chunk

    // stage a FULL nt (64 codes x 256 ch = 4 slabs x 8 KB) into buffer P
#define STAGE_NT(P, NT)                                                        \
    do {                                                                       \
        _Pragma("unroll")                                                      \
        for (int s_ = 0; s_ < 4; ++s_) {                                       \
            char* dst = (char*)Bsm[P][s_] + wave * 1024;                       \
            const size_t bOff = (size_t)(codeQ + (NT) * 64 + srow) * 256       \
                                + s_ * 64 + sch * 8;                           \
            _Pragma("unroll")                                                  \
            for (int it = 0; it < 2; ++it)                                     \
                gld16(B2 + bOff + (size_t)it * (32 * 256), dst + it * 4096);   \
        }                                                                      \
    } while (0)

    unsigned K1[2][4], K2[2][4];
    #pragma unroll
    for (int i = 0; i < 2; ++i)
        #pragma unroll
        for (int r = 0; r < 4; ++r) { K1[i][r] = 0u; K2[i][r] = 0u; }

    STAGE_NT(0, 0);                 // prologue prefetch (with hn loads in flight)
    __syncthreads();                // drains all prologue vmem, once

    #pragma unroll 1
    for (int nt = 0; nt < 32; ++nt) {
        // prefetch nt+1 into the other buffer; flies under this nt's compute
        if (nt + 1 < 32) STAGE_NT((nt + 1) & 1, nt + 1);

        // acc init = hn = -(0.5||e||^2 + 256): MFMA output IS the biased score
        const int hb = nt * 64 + l15;
        f32x4 acc[2][4];
        #pragma unroll
        for (int j = 0; j < 4; ++j) {
            const float nh = hn_sm[hb + j * 16];
            #pragma unroll
            for (int i = 0; i < 2; ++i) {
                f32x4 z = {nh, nh, nh, nh};
                acc[i][j] = z;
            }
        }

        #pragma unroll
        for (int st = 0; st < 4; ++st) {
            const char* bs = (const char*)Bsm[nt & 1][st];
            #pragma unroll
            for (int ks2 = 0; ks2 < 2; ++ks2) {
                bf16x8 bfr[4];
                #pragma unroll
                for (int j = 0; j < 4; ++j) {
                    const int rowB = j * 16 + l15;
                    const int cbk = ((quad ^ (rowB & 7)) ^ (ks2 << 2)) * 16;
                    bfr[j] = *(const bf16x8*)(bs + rowB * 128 + cbk);
                }
                const int ka = st * 2 + ks2;           // K-chunk 0..7
                #pragma unroll
                for (int i = 0; i < 2; ++i)
                    #pragma unroll
                    for (int j = 0; j < 4; ++j)        // x·e (single product)
                        acc[i][j] = __builtin_amdgcn_mfma_f32_16x16x32_bf16(
                            af[i][ka], bfr[j], acc[i][j], 0, 0, 0);
            }
        }

        // epilogue: branchless packed-key top-2 (all scores negative)
        // key = (~bits & 0xFFFFF800) | (2047 - local_code)
        const int icb = 2047 - (nt * 64 + l15);
        #pragma unroll
        for (int j = 0; j < 4; ++j) {
            const unsigned ic = (unsigned)(icb - j * 16);
            #pragma unroll
            for (int i = 0; i < 2; ++i)
                #pragma unroll
                for (int r = 0; r < 4; ++r) {
                    const unsigned u = __float_as_uint(acc[i][j][r]);
                    const unsigned k = (~u & 0xFFFFF800u) | ic;
                    const unsigned lo = min(k, K1[i][r]);
                    K1[i][r] = max(k, K1[i][r]);
                    K2[i][r] = max(K2[i][r], lo);
                }
        }

        __syncthreads();   // all waves done reading buf[nt&1]; nt+1 staged
    }
#undef STAGE_NT

    // top-2 butterfly across the 16-lane col groups (same tokens)
    #pragma unroll
    for (int off = 1; off < 16; off <<= 1) {
        #pragma unroll
        for (int i = 0; i < 2; ++i)
            #pragma unroll
            for (int r = 0; r < 4; ++r) {
                const unsigned t1 = __shfl_xor(K1[i][r], off);
                const unsigned t2 = __shfl_xor(K2[i][r], off);
                const unsigned lo = min(K1[i][r], t1);
                K1[i][r] = max(K1[i][r], t1);
                K2[i][r] = max(max(K2[i][r], t2), lo);
            }
    }

    // l15==0 lanes hold finals for tokens mblk*128 + wave*32 + i*16 + quad*4 + r
    if (l15 == 0) {
        #pragma unroll
        for (int i = 0; i < 2; ++i)
            #pragma unroll
            for (int r = 0; r < 4; ++r) {
                const int tok = mblk * 128 + wave * 32 + i * 16 + quad * 4 + r;
                const int gi = nq * NN + tok;
                pk1[gi] = K1[i][r]; pk2[gi] = K2[i][r];
            }
    }
}

// ---------------------------------------------------------------------------
// Finalize v5: 512 threads/block.
//   A) merge 8 per-quarter packed keys -> top-3 candidates (wave 0)
//   B) stage x transposed, 8 channel-groups of 32 (coalesced)
//   R) fp64 rescore of 3 candidates, 8 threads/token (32 ch each)
//   P) pick true min of 3 (wave 0), idx write, one loss atomic
//   C) load chosen code rows row-contiguous (8 waves x 8 tokens)
//   D) write qe coalesced
// ---------------------------------------------------------------------------
__global__ __launch_bounds__(512) void finalize_kernel(const float* __restrict__ x,
                                                       const float* __restrict__ cb,
                                                       const unsigned* __restrict__ pk1,
                                                       const unsigned* __restrict__ pk2,
                                                       float* __restrict__ qe,
                                                       float* __restrict__ idx_f,
                                                       float* __restrict__ loss) {
    __shared__ float  xt[256 * 65];     // [c][tok] transposed tile, 65-pad; reused for e rows
    __shared__ int    cnd[3][64], bsx[64];
    __shared__ double dp[3][8][64];     // [cand][cq][tok]

    const int t = threadIdx.x;
    const int n0 = blockIdx.x * 64;
    const int b = n0 >> 10, hw0 = n0 & 1023;
    const int tok_l = t & 63, cg = t >> 6;      // cg in [0,8)

    // Phase A: top-3 of the 8 per-quarter packed candidates (wave 0)
    if (t < 64) {
        unsigned s1 = 0u, s2 = 0u, s3 = 0u;
        int i1 = 0x7ffffff, i2 = 0x7ffffff, i3 = 0x7ffffff;
        const int n = n0 + t;
        #pragma unroll
        for (int q = 0; q < 4; ++q) {
            const unsigned ka = pk1[q * NN + n];
            const unsigned kb = pk2[q * NN + n];
            const int ga = q * 2048 + 2047 - (int)(ka & 2047u);
            const int gb = q * 2048 + 2047 - (int)(kb & 2047u);
            top3k_insert(s1, i1, s2, i2, s3, i3, ka, ga);
            top3k_insert(s1, i1, s2, i2, s3, i3, kb, gb);
        }
        cnd[0][t] = i1; cnd[1][t] = i2; cnd[2][t] = i3;
    }

    // Phase B: stage x transposed, fully coalesced (lane = hw); 32 ch/group
    const float* xb = x + ((size_t)b << 18) + hw0 + tok_l;
    #pragma unroll 8
    for (int i = 0; i < 32; ++i) {
        const int c = cg * 32 + i;
        xt[c * 65 + tok_l] = xb[(size_t)c << 10];
    }
    __syncthreads();

    // Phase R: fp64 rescore of the 3 candidates; 8 threads per token
    {
        const int tok = t & 63, cq = t >> 6;
        const float* c0 = cb + (size_t)cnd[0][tok] * CCH + cq * 32;
        const float* c1 = cb + (size_t)cnd[1][tok] * CCH + cq * 32;
        const float* c2 = cb + (size_t)cnd[2][tok] * CCH + cq * 32;
        double d0 = 0.0, d1 = 0.0, d2 = 0.0;
        #pragma unroll
        for (int j = 0; j < 32; j += 4) {
            const f32x4 e0 = *(const f32x4*)(c0 + j);
            const f32x4 e1 = *(const f32x4*)(c1 + j);
            const f32x4 e2 = *(const f32x4*)(c2 + j);
            #pragma unroll
            for (int u = 0; u < 4; ++u) {
                const float xv = xt[(cq * 32 + j + u) * 65 + tok];
                const double dx0 = (double)xv - (double)e0[u];
                const double dx1 = (double)xv - (double)e1[u];
                const double dx2 = (double)xv - (double)e2[u];
                d0 += dx0 * dx0;
                d1 += dx1 * dx1;
                d2 += dx2 * dx2;
            }
        }
        dp[0][cq][tok] = d0; dp[1][cq][tok] = d1; dp[2][cq][tok] = d2;
    }
    __syncthreads();

    // Phase P: pick true min of the 3 per token (wave 0), idx, loss atomic
    if (t < 64) {
        double dd[3]; int ii[3];
        #pragma unroll
        for (int c = 0; c < 3; ++c) {
            double s = 0.0;
            #pragma unroll
            for (int q = 0; q < 8; ++q) s += dp[c][q][t];
            dd[c] = s;
            ii[c] = cnd[c][t];
        }
        int bi = ii[0]; double bd = dd[0];
        if (dd[1] < bd || (dd[1] == bd && ii[1] < bi)) { bd = dd[1]; bi = ii[1]; }
        if (dd[2] < bd || (dd[2] == bd && ii[2] < bi)) { bd = dd[2]; bi = ii[2]; }
        bsx[t] = bi;
        idx_f[n0 + t] = (float)bi;
        float lsum = (float)bd;
        #pragma unroll
        for (int off = 32; off; off >>= 1) lsum += __shfl_down(lsum, off);
        if (t == 0) atomicAdd(loss, lsum * (1.0f / ((float)NN * (float)CCH)));
    }
    __syncthreads();

    // Phase C: load chosen code rows (row-contiguous, coalesced) into xt
    {
        const int w = t >> 6, lane = t & 63;     // 8 waves x 8 tokens
        #pragma unroll
        for (int i = 0; i < 8; ++i) {
            const int tok = w * 8 + i;
            const float* e = cb + (size_t)bsx[tok] * CCH;
            #pragma unroll
            for (int u = 0; u < 4; ++u) {
                const int c = u * 64 + lane;
                xt[c * 65 + tok] = e[c];
            }
        }
    }
    __syncthreads();

    // Phase D: write qe coalesced from the transposed LDS (lane = hw)
    float* qb = qe + ((size_t)b << 18) + hw0 + tok_l;
    #pragma unroll 8
    for (int i = 0; i < 32; ++i) {
        const int c = cg * 32 + i;
        qb[(size_t)c << 10] = xt[c * 65 + tok_l];
    }
}

// ---------------------------------------------------------------------------
extern "C" void kernel_launch(void* const* d_in, const int* in_sizes, int n_in,
                              void* d_out, int out_size, void* d_ws, size_t ws_size,
                              hipStream_t stream) {
    const float* x  = (const float*)d_in[0];
    const float* cb = (const float*)d_in[1];
    float* out = (float*)d_out;
    char* ws = (char*)d_ws;

    // A (frag-major bf16) lives in d_out's qe region; finalize rewrites qe.
    unsigned short* A  = (unsigned short*)out;
    unsigned short* B2 = (unsigned short*)(ws + B2_OFF);
    float* hn  = (float*)(ws + HN_OFF);
    unsigned* pk1 = (unsigned*)(ws + PK1_OFF);
    unsigned* pk2 = (unsigned*)(ws + PK2_OFF);

    prep_kernel    <<<256 + KK / 8, 256, 0, stream>>>(x, cb, A, B2, hn,
                                                      out + LOSS_OFF);
    vq_gemm_kernel <<<512, 256, 0, stream>>>(A, B2, hn, pk1, pk2);
    finalize_kernel<<<NN / 64, 512, 0, stream>>>(x, cb, pk1, pk2,
                                                 out, out + IDX_OFF,
                                                 out + LOSS_OFF);
}